// Round 9
// baseline (285.362 us; speedup 1.0000x reference)
//
#include <hip/hip_runtime.h>
#include <stdint.h>

#define NA 200000
#define NB 8
#define NM 64
#define APB 512                 // anchors per k_main block (2 per thread) -- r6/r8 proven config
#define CPB 391                 // 391*512 = 200192 >= 200000
#define NA4 50000               // NA/4 uint4 per image
#define SPB 128                 // scan blocks per image (T1)

// ---- workspace layout (dword offsets) ----
// scal: 8 images x 16 slots: [0]np [1]nn [2]ps(f32) [3]bs(f32) [6]compact_count
#define O_SCAL 0
#define O_L1C  128                   // 8 x 256
#define O_L1S  2176
#define O_L2C  4224                  // 8 x 4096 (byte 16896, 16B-aligned)
#define O_L2S  36992
#define O_KEYS 69760                 // 8 x 200000
#define O_CBUF 1669760               // 8 x 200000 compacted keys (worst case = all)
#define N_ZERO 69760                 // zero scal + L1 + L2 (279 KB)

__device__ __forceinline__ unsigned int f2key(float f) {
    unsigned int u = __float_as_uint(f);
    return (u & 0x80000000u) ? ~u : (u | 0x80000000u);
}
__device__ __forceinline__ float key2f(unsigned int k) {
    return (k & 0x80000000u) ? __uint_as_float(k & 0x7fffffffu) : __uint_as_float(~k);
}
__device__ __forceinline__ unsigned int calck(const unsigned int* scal, int b) {
    const unsigned int np = scal[b * 16], nn = scal[b * 16 + 1];
    if (!np) return 0u;
    const unsigned int kp = np * 3u;
    return (kp < nn) ? kp : nn;
}

// barrier-free select over a 256-bin (cnt,sum) histogram: one wave, 4 bins/lane.
// All 64 lanes must be active. Integer counts -> c/cab bit-deterministic.
__device__ __forceinline__ void wave_sel256(
    const unsigned int* __restrict__ cnt, const float* __restrict__ sum,
    unsigned int target, unsigned int* c, unsigned int* cab, float* sab)
{
    const int lane = (int)(threadIdx.x & 63u);
    const uint4  c4 = ((const uint4*)cnt)[lane];
    const float4 s4 = ((const float4*)sum)[lane];
    unsigned int S = c4.x + c4.y + c4.z + c4.w;
    float Sf = s4.x + s4.y + s4.z + s4.w;
    for (int d = 1; d < 64; d <<= 1) {           // inclusive suffix scan across lanes
        const unsigned int oc = __shfl_down(S, d);
        const float of = __shfl_down(Sf, d);
        if (lane + d < 64) { S += oc; Sf += of; }
    }
    unsigned int Sn = __shfl_down(S, 1);          // suffix strictly above this lane's bins
    float Sfn = __shfl_down(Sf, 1);
    if (lane == 63) { Sn = 0u; Sfn = 0.0f; }
    const unsigned int cb[4] = {c4.x, c4.y, c4.z, c4.w};
    const float sb[4] = {s4.x, s4.y, s4.z, s4.w};
    unsigned int run = Sn; float runs = Sfn;
    bool found = false; unsigned int lc = 0, lcab = 0; float lsab = 0.0f;
#pragma unroll
    for (int j = 3; j >= 0; --j) {
        const unsigned int prev = run; const float prevs = runs;
        run += cb[j]; runs += sb[j];
        if (run >= target && prev < target) {
            found = true; lc = (unsigned int)(4 * lane + j); lcab = prev; lsab = prevs;
        }
    }
    const unsigned long long m = __ballot(found);
    const int src = __ffsll((long long)m) - 1;
    *c = __shfl(lc, src); *cab = __shfl(lcab, src); *sab = __shfl(lsab, src);
}

// exact select over 4096-bin GLOBAL hist; 1024-thread block, threads<256 active (guarded).
__device__ void sel4096g_g(const unsigned int* cnt, const float* sum, unsigned int target,
                           unsigned int* s_sc, float* s_ss, unsigned int* s_res, float* s_resf,
                           unsigned int* c, unsigned int* cab, float* sab) {
    const int t = threadIdx.x;
    unsigned int cb[16]; float sb[16];
    if (t < 256) {
        const uint4*  cp = (const uint4*)(cnt + t * 16);
        const float4* sp = (const float4*)(sum + t * 16);
#pragma unroll
        for (int j = 0; j < 4; ++j) {
            uint4 u = cp[j];  cb[4*j] = u.x; cb[4*j+1] = u.y; cb[4*j+2] = u.z; cb[4*j+3] = u.w;
            float4 f = sp[j]; sb[4*j] = f.x; sb[4*j+1] = f.y; sb[4*j+2] = f.z; sb[4*j+3] = f.w;
        }
        unsigned int cc = 0; float cs = 0.0f;
#pragma unroll
        for (int j = 0; j < 16; ++j) { cc += cb[j]; cs += sb[j]; }
        s_sc[t] = cc; s_ss[t] = cs;
    }
    __syncthreads();
    for (int d = 1; d < 256; d <<= 1) {
        unsigned int uc = 0; float fs = 0.0f;
        if (t < 256) { uc = (t + d < 256) ? s_sc[t + d] : 0u; fs = (t + d < 256) ? s_ss[t + d] : 0.0f; }
        __syncthreads();
        if (t < 256) { s_sc[t] += uc; s_ss[t] += fs; }
        __syncthreads();
    }
    if (t < 256) {
        unsigned int run = (t < 255) ? s_sc[t + 1] : 0u;
        float runs = (t < 255) ? s_ss[t + 1] : 0.0f;
#pragma unroll
        for (int j = 15; j >= 0; --j) {
            const unsigned int prev = run; const float prevs = runs;
            run += cb[j]; runs += sb[j];
            if (run >= target && prev < target) {
                s_res[0] = (unsigned int)(t * 16 + j); s_res[1] = prev; *s_resf = prevs;
            }
        }
    }
    __syncthreads();
    *c = s_res[0]; *cab = s_res[1]; *sab = *s_resf;
    __syncthreads();
}

// exact select over 4096-bin LDS hist; 1024-thread block, threads<256 active (guarded).
__device__ void sel4096_lds(const unsigned int* hc, const float* hs, unsigned int target,
                            unsigned int* s_sc, float* s_ss, unsigned int* s_res, float* s_resf,
                            unsigned int* c, unsigned int* cab, float* sab)
{
    const int t = threadIdx.x;
    unsigned int cb[16]; float sb[16];
    if (t < 256) {
        unsigned int cc = 0; float cs = 0.0f;
#pragma unroll
        for (int j = 0; j < 16; ++j) {
            cb[j] = hc[t * 16 + j]; sb[j] = hs[t * 16 + j];
            cc += cb[j]; cs += sb[j];
        }
        s_sc[t] = cc; s_ss[t] = cs;
    }
    __syncthreads();
    for (int d = 1; d < 256; d <<= 1) {
        unsigned int uc = 0; float fs = 0.0f;
        if (t < 256) { uc = (t + d < 256) ? s_sc[t + d] : 0u; fs = (t + d < 256) ? s_ss[t + d] : 0.0f; }
        __syncthreads();
        if (t < 256) { s_sc[t] += uc; s_ss[t] += fs; }
        __syncthreads();
    }
    if (t < 256) {
        unsigned int run = (t < 255) ? s_sc[t + 1] : 0u;
        float runs = (t < 255) ? s_ss[t + 1] : 0.0f;
#pragma unroll
        for (int j = 15; j >= 0; --j) {
            const unsigned int prev = run; const float prevs = runs;
            run += cb[j]; runs += sb[j];
            if (run >= target && prev < target) {
                s_res[0] = (unsigned int)(t * 16 + j); s_res[1] = prev; *s_resf = prevs;
            }
        }
    }
    __syncthreads();
    *c = s_res[0]; *cab = s_res[1]; *sab = *s_resf;
    __syncthreads();
}

// per-anchor epilogue: key write + LDS L1 hist + pos-path box loss accumulation
__device__ __forceinline__ void epi(
    int b, int i, float4 a4, int arg, bool pos, bool neg,
    const float* __restrict__ cls, const float* __restrict__ reg,
    const float4* sbox, unsigned int* __restrict__ keys,
    unsigned int* hc8, float* hs8, float& posv, float& boxv)
{
    const float2 cv = ((const float2*)cls)[(size_t)b * NA + i];
    unsigned int key = 0u;   // excluded anchors: key 0
    if (neg) {
        const float nl = -cv.y;
        key = f2key(nl);
        atomicAdd(&hc8[key >> 24], 1u);
        atomicAdd(&hs8[key >> 24], nl);
    }
    keys[(size_t)b * NA + i] = key;
    if (pos) {
        posv += -cv.x;
        const float4 g = sbox[arg];
        const float aw = a4.z - a4.x, ah = a4.w - a4.y;
        const float acx = a4.x + 0.5f * aw, acy = a4.y + 0.5f * ah;
        const float gw = g.z - g.x, gh = g.w - g.y;
        const float gcx = g.x + 0.5f * gw, gcy = g.y + 0.5f * gh;
        const float t0 = ((gcx - acx) / (aw + 1e-14f)) / 0.1f;
        const float t1 = ((gcy - acy) / (ah + 1e-14f)) / 0.1f;
        const float t2 = logf(gw / aw) / 0.2f;
        const float t3 = logf(gh / ah) / 0.2f;
        const float4 r = ((const float4*)reg)[(size_t)b * NA + i];
        const float d0 = fabsf(t0 - r.x);
        const float d1 = fabsf(t1 - r.y);
        const float d2 = fabsf(t2 - r.z);
        const float d3 = fabsf(t3 - r.w);
        const float l0 = (d0 < 1.0f) ? 0.5f * d0 * d0 : d0 - 0.5f;
        const float l1 = (d1 < 1.0f) ? 0.5f * d1 * d1 : d1 - 0.5f;
        const float l2 = (d2 < 1.0f) ? 0.5f * d2 * d2 : d2 - 0.5f;
        const float l3 = (d3 < 1.0f) ? 0.5f * d3 * d3 : d3 - 0.5f;
        boxv += l0 + l1 + l2 + l3;
    }
}

// ---------------- K1: UNCHANGED r8 config (2 anchors/thread, 8-box register stages) -----------
__global__ __launch_bounds__(256, 4) void k_main(
    const float* __restrict__ cls, const float* __restrict__ reg,
    const float* __restrict__ anchors, const float* __restrict__ ann,
    unsigned int* __restrict__ scal, unsigned int* __restrict__ l1cnt,
    float* __restrict__ l1sum, unsigned int* __restrict__ keys)
{
    __shared__ float4 sbox[NM];
    __shared__ unsigned int hc8[256];
    __shared__ float hs8[256];
    __shared__ unsigned int s_np, s_nn;
    __shared__ float s_ps, s_bs;

    const int b = blockIdx.y;
    const int tid = threadIdx.x;
    if (tid < NM) {
        float4 bb = ((const float4*)ann)[b * NM + tid];
        if (!(bb.x > 0.0f)) {   // invalid -> inter 0, ua inf, ratio 0 (bit-exact vs ref, r3-r8)
            bb.x = __builtin_inff(); bb.y = __builtin_inff();
            bb.z = -__builtin_inff(); bb.w = -__builtin_inff();
        }
        sbox[tid] = bb;
    }
    hc8[tid] = 0u; hs8[tid] = 0.0f;
    if (tid == 0) { s_np = 0u; s_nn = 0u; s_ps = 0.0f; s_bs = 0.0f; }
    __syncthreads();

    const int i0 = blockIdx.x * APB + tid;
    const int i1 = i0 + 256;
    float4 A0 = make_float4(0.f, 0.f, 0.f, 0.f);
    float4 A1 = make_float4(0.f, 0.f, 0.f, 0.f);
    if (i0 < NA) A0 = ((const float4*)anchors)[i0];
    if (i1 < NA) A1 = ((const float4*)anchors)[i1];

    float bi0 = -1.0f, bu0 = 1.0f, bi1 = -1.0f, bu1 = 1.0f;
    int arg0 = 0, arg1 = 0;
    bool pos0, neg0, pos1, neg1;
    {
#pragma clang fp contract(off)
        const float aa0 = (A0.z - A0.x) * (A0.w - A0.y);
        const float aa1 = (A1.z - A1.x) * (A1.w - A1.y);
#pragma unroll 1
        for (int mo = 0; mo < NM; mo += 8) {
            float4 bb[8]; float ab[8];
#pragma unroll
            for (int j = 0; j < 8; ++j) {
                bb[j] = sbox[mo + j];
                ab[j] = (bb[j].z - bb[j].x) * (bb[j].w - bb[j].y);
            }
#pragma unroll
            for (int j = 0; j < 8; ++j) {
                {
                    const float iw = fmaxf(fminf(A0.z, bb[j].z) - fmaxf(A0.x, bb[j].x), 0.0f);
                    const float ih = fmaxf(fminf(A0.w, bb[j].w) - fmaxf(A0.y, bb[j].y), 0.0f);
                    const float inter = iw * ih;
                    const float ua = fmaxf(aa0 + ab[j] - inter, 1e-8f);
                    if (inter * bu0 > bi0 * ua) { bi0 = inter; bu0 = ua; arg0 = mo + j; }
                }
                {
                    const float iw = fmaxf(fminf(A1.z, bb[j].z) - fmaxf(A1.x, bb[j].x), 0.0f);
                    const float ih = fmaxf(fminf(A1.w, bb[j].w) - fmaxf(A1.y, bb[j].y), 0.0f);
                    const float inter = iw * ih;
                    const float ua = fmaxf(aa1 + ab[j] - inter, 1e-8f);
                    if (inter * bu1 > bi1 * ua) { bi1 = inter; bu1 = ua; arg1 = mo + j; }
                }
            }
        }
        pos0 = (bi0 >= 0.5f * bu0); neg0 = (bi0 < 0.3f * bu0);
        pos1 = (bi1 >= 0.5f * bu1); neg1 = (bi1 < 0.3f * bu1);
    }

    float posv = 0.0f, boxv = 0.0f;
    if (i0 < NA) epi(b, i0, A0, arg0, pos0, neg0, cls, reg, (const float4*)sbox, keys, hc8, hs8, posv, boxv);
    else { pos0 = false; neg0 = false; }
    if (i1 < NA) epi(b, i1, A1, arg1, pos1, neg1, cls, reg, (const float4*)sbox, keys, hc8, hs8, posv, boxv);
    else { pos1 = false; neg1 = false; }

    const unsigned long long pb0 = __ballot(pos0);
    const unsigned long long pb1 = __ballot(pos1);
    const unsigned long long nb0 = __ballot(neg0);
    const unsigned long long nb1 = __ballot(neg1);
    if (pb0 | pb1) {
        for (int off = 32; off; off >>= 1) {
            posv += __shfl_xor(posv, off);
            boxv += __shfl_xor(boxv, off);
        }
    }
    if ((tid & 63) == 0) {
        const unsigned int nc = (unsigned int)(__popcll(nb0) + __popcll(nb1));
        const unsigned int pc = (unsigned int)(__popcll(pb0) + __popcll(pb1));
        if (nc) atomicAdd(&s_nn, nc);
        if (pc) { atomicAdd(&s_np, pc); atomicAdd(&s_ps, posv); atomicAdd(&s_bs, boxv); }
    }
    __syncthreads();
    unsigned int* sg = scal + b * 16;
    if (tid == 0) {
        if (s_nn) atomicAdd(&sg[1], s_nn);
        if (s_np) {
            atomicAdd(&sg[0], s_np);
            atomicAdd((float*)(sg + 2), s_ps);
            atomicAdd((float*)(sg + 3), s_bs);
        }
    }
    if (hc8[tid]) {
        atomicAdd(&l1cnt[b * 256 + tid], hc8[tid]);
        atomicAdd(&l1sum[b * 256 + tid], hs8[tid]);
    }
}

// ---------------- T1: L2 hist + compaction of c1-bin keys (128 blocks/image) ----------------
__global__ __launch_bounds__(256) void k_h2c(
    const unsigned int* __restrict__ keys, unsigned int* __restrict__ scal,
    const unsigned int* __restrict__ l1c, const float* __restrict__ l1s,
    unsigned int* __restrict__ l2c, float* __restrict__ l2s,
    unsigned int* __restrict__ cbuf)
{
    const int b = blockIdx.x >> 7;
    const int sub = blockIdx.x & (SPB - 1);
    const int tid = threadIdx.x;
    const unsigned int k = calck(scal, b);
    if (k == 0) return;   // grid-uniform per image
    unsigned int c1, cab1; float sab1;
    wave_sel256(l1c + b * 256, l1s + b * 256, k, &c1, &cab1, &sab1);   // barrier-free

    const uint4* kp4 = (const uint4*)(keys + (size_t)b * NA);
    const int j0 = sub * 256 + tid;          // [0, 32767] < NA4
    const int j1 = j0 + SPB * 256;           // [32768, 65535]
    const uint4 v0 = kp4[j0];
    const uint4 v1 = (j1 < NA4) ? kp4[j1] : make_uint4(0, 0, 0, 0);
    const unsigned int kk[8] = {v0.x, v0.y, v0.z, v0.w, v1.x, v1.y, v1.z, v1.w};
    unsigned int* cnt = scal + b * 16 + 6;
    unsigned int* cb = cbuf + (size_t)b * NA;
    const int lane = tid & 63;
#pragma unroll
    for (int j = 0; j < 8; ++j) {
        const unsigned int key = kk[j];
        const bool m = key && (key >> 24) == c1;
        if (m) {
            const unsigned int bin = (key >> 12) & 0xfffu;
            atomicAdd(&l2c[b * 4096 + bin], 1u);
            atomicAdd(&l2s[b * 4096 + bin], key2f(key));
        }
        const unsigned long long mask = __ballot(m);
        if (mask) {   // wave-aggregated append
            const int leader = __ffsll((long long)mask) - 1;
            unsigned int base = 0u;
            if (lane == leader) base = atomicAdd(cnt, (unsigned int)__popcll(mask));
            base = __shfl(base, leader);
            if (m) cb[base + (unsigned int)__popcll(mask & ((1ull << lane) - 1ull))] = key;
        }
    }
}

// ---------------- T2: sel2 over L2 + single pass over compacted keys + finalize (8 blocks) ----
__global__ __launch_bounds__(1024) void k_fin2(
    unsigned int* __restrict__ scal,
    const unsigned int* __restrict__ l1c, const float* __restrict__ l1s,
    const unsigned int* __restrict__ l2c, const float* __restrict__ l2s,
    const unsigned int* __restrict__ cbuf, float* __restrict__ out)
{
    __shared__ unsigned int hc[4096];
    __shared__ float hs[4096];
    __shared__ unsigned int s_sc[256];
    __shared__ float s_ss[256];
    __shared__ unsigned int s_res[2];
    __shared__ float s_resf;

    const int b = blockIdx.x;
    const int tid = threadIdx.x;
    const unsigned int np = scal[b * 16];
    const unsigned int k = calck(scal, b);
    float s_top = 0.0f;

    if (k > 0) {   // block-uniform
        unsigned int c1, cab1; float sab1;
        wave_sel256(l1c + b * 256, l1s + b * 256, k, &c1, &cab1, &sab1);   // every wave, redundant
        const unsigned int t2 = k - cab1;
        unsigned int c2, cab2; float sab2;
        sel4096g_g(l2c + b * 4096, l2s + b * 4096, t2, s_sc, s_ss, s_res, &s_resf, &c2, &cab2, &sab2);
        const unsigned int t3 = t2 - cab2;
        const unsigned int top20 = (c1 << 12) | c2;
        const unsigned int n2 = scal[b * 16 + 6];

        for (int j = tid; j < 4096; j += 1024) { hc[j] = 0u; hs[j] = 0.0f; }
        __syncthreads();
        const unsigned int* cb = cbuf + (size_t)b * NA;
        for (unsigned int base = 0; base < n2; base += 4096) {
            const unsigned int i0 = base + tid, i1 = i0 + 1024, i2 = i0 + 2048, i3 = i0 + 3072;
            const unsigned int k0 = (i0 < n2) ? cb[i0] : 0u;
            const unsigned int k1 = (i1 < n2) ? cb[i1] : 0u;
            const unsigned int k2 = (i2 < n2) ? cb[i2] : 0u;
            const unsigned int k3 = (i3 < n2) ? cb[i3] : 0u;
            const unsigned int kk[4] = {k0, k1, k2, k3};
#pragma unroll
            for (int j = 0; j < 4; ++j) {
                const unsigned int key = kk[j];
                if (key && (key >> 12) == top20) {
                    const unsigned int bin = key & 0xfffu;
                    atomicAdd(&hc[bin], 1u);
                    atomicAdd(&hs[bin], key2f(key));
                }
            }
        }
        __syncthreads();
        unsigned int c3, cab3; float sab3;
        sel4096_lds(hc, hs, t3, s_sc, s_ss, s_res, &s_resf, &c3, &cab3, &sab3);

        const unsigned int keyv = (c1 << 24) | (c2 << 12) | c3;
        const float v = key2f(keyv);
        const unsigned int rem = t3 - cab3;      // exact tie handling: leaf keys identical
        s_top = sab1 + sab2 + sab3 + (float)rem * v;
    }

    if (tid == 0) {
        float cls_loss = 0.0f, box_loss = 0.0f;
        if (np > 0) {
            const float* fsc = (const float*)(scal + b * 16);
            const float pos_mean = fsc[2] / (float)np;
            const float neg_mean = s_top / (float)((k > 0) ? k : 1u);
            cls_loss = pos_mean + neg_mean;
            box_loss = fsc[3] / (float)(4u * np);
        }
        out[b] = cls_loss;
        out[NB + b] = box_loss;
    }
}

extern "C" void kernel_launch(void* const* d_in, const int* in_sizes, int n_in,
                              void* d_out, int out_size, void* d_ws, size_t ws_size,
                              hipStream_t stream) {
    const float* cls     = (const float*)d_in[0];   // (B, A, 2)
    const float* reg     = (const float*)d_in[1];   // (B, A, 4)
    const float* anchors = (const float*)d_in[2];   // (1, A, 4)
    const float* ann     = (const float*)d_in[3];   // (B, M, 4)
    unsigned int* ws = (unsigned int*)d_ws;
    unsigned int* scal = ws + O_SCAL;
    unsigned int* l1c  = ws + O_L1C;   float* l1s = (float*)(ws + O_L1S);
    unsigned int* l2c  = ws + O_L2C;   float* l2s = (float*)(ws + O_L2S);
    unsigned int* keys = ws + O_KEYS;
    unsigned int* cbuf = ws + O_CBUF;
    (void)in_sizes; (void)n_in; (void)out_size; (void)ws_size;

    hipMemsetAsync(d_ws, 0, (size_t)N_ZERO * 4, stream);
    k_main<<<dim3(CPB, NB),  256,  0, stream>>>(cls, reg, anchors, ann, scal, l1c, l1s, keys);
    k_h2c <<<dim3(NB * SPB), 256,  0, stream>>>(keys, scal, l1c, l1s, l2c, l2s, cbuf);
    k_fin2<<<dim3(NB),       1024, 0, stream>>>(scal, l1c, l1s, l2c, l2s, cbuf, (float*)d_out);
}

// Round 10
// 269.754 us; speedup vs baseline: 1.0579x; 1.0579x over previous
//
#include <hip/hip_runtime.h>
#include <stdint.h>

#define NA 200000
#define NB 8
#define NM 64
#define APB 512                 // anchors per k_main block (2 per thread) -- r6/r8 proven config
#define CPB 391                 // 391*512 = 200192 >= 200000
#define NA4 50000               // NA/4 uint4 per image
#define SPB 128                 // scan blocks per image (k_h2c)

// ---- workspace layout (dword offsets) ----
// scal: 8 images x 16 slots: [0]np [1]nn [2]ps(f32) [3]bs(f32) [6]compact_count
#define O_SCAL 0
#define O_L1C  128                   // 8 x 256
#define O_L1S  2176
#define O_KEYS 4224                  // 8 x 200000 (byte 16896, 16B-aligned)
#define O_CBUF 1604224               // 8 x 200000 compacted keys (worst case = all)
#define N_ZERO 4224                  // zero scal + L1 only (16.9 KB)

__device__ __forceinline__ unsigned int f2key(float f) {
    unsigned int u = __float_as_uint(f);
    return (u & 0x80000000u) ? ~u : (u | 0x80000000u);
}
__device__ __forceinline__ float key2f(unsigned int k) {
    return (k & 0x80000000u) ? __uint_as_float(k & 0x7fffffffu) : __uint_as_float(~k);
}
__device__ __forceinline__ unsigned int calck(const unsigned int* scal, int b) {
    const unsigned int np = scal[b * 16], nn = scal[b * 16 + 1];
    if (!np) return 0u;
    const unsigned int kp = np * 3u;
    return (kp < nn) ? kp : nn;
}

// barrier-free select over a 256-bin (cnt,sum) histogram: one wave, 4 bins/lane.
// All 64 lanes must be active. Integer counts -> c/cab bit-deterministic. (r9-verified)
__device__ __forceinline__ void wave_sel256(
    const unsigned int* __restrict__ cnt, const float* __restrict__ sum,
    unsigned int target, unsigned int* c, unsigned int* cab, float* sab)
{
    const int lane = (int)(threadIdx.x & 63u);
    const uint4  c4 = ((const uint4*)cnt)[lane];
    const float4 s4 = ((const float4*)sum)[lane];
    unsigned int S = c4.x + c4.y + c4.z + c4.w;
    float Sf = s4.x + s4.y + s4.z + s4.w;
    for (int d = 1; d < 64; d <<= 1) {           // inclusive suffix scan across lanes
        const unsigned int oc = __shfl_down(S, d);
        const float of = __shfl_down(Sf, d);
        if (lane + d < 64) { S += oc; Sf += of; }
    }
    unsigned int Sn = __shfl_down(S, 1);          // suffix strictly above this lane's bins
    float Sfn = __shfl_down(Sf, 1);
    if (lane == 63) { Sn = 0u; Sfn = 0.0f; }
    const unsigned int cb[4] = {c4.x, c4.y, c4.z, c4.w};
    const float sb[4] = {s4.x, s4.y, s4.z, s4.w};
    unsigned int run = Sn; float runs = Sfn;
    bool found = false; unsigned int lc = 0, lcab = 0; float lsab = 0.0f;
#pragma unroll
    for (int j = 3; j >= 0; --j) {
        const unsigned int prev = run; const float prevs = runs;
        run += cb[j]; runs += sb[j];
        if (run >= target && prev < target) {
            found = true; lc = (unsigned int)(4 * lane + j); lcab = prev; lsab = prevs;
        }
    }
    const unsigned long long m = __ballot(found);
    const int src = __ffsll((long long)m) - 1;
    *c = __shfl(lc, src); *cab = __shfl(lcab, src); *sab = __shfl(lsab, src);
}

// exact select over 4096-bin LDS hist; 1024-thread block, threads<256 active (guarded).
__device__ void sel4096_lds(const unsigned int* hc, const float* hs, unsigned int target,
                            unsigned int* s_sc, float* s_ss, unsigned int* s_res, float* s_resf,
                            unsigned int* c, unsigned int* cab, float* sab)
{
    const int t = threadIdx.x;
    unsigned int cb[16]; float sb[16];
    if (t < 256) {
        unsigned int cc = 0; float cs = 0.0f;
#pragma unroll
        for (int j = 0; j < 16; ++j) {
            cb[j] = hc[t * 16 + j]; sb[j] = hs[t * 16 + j];
            cc += cb[j]; cs += sb[j];
        }
        s_sc[t] = cc; s_ss[t] = cs;
    }
    __syncthreads();
    for (int d = 1; d < 256; d <<= 1) {
        unsigned int uc = 0; float fs = 0.0f;
        if (t < 256) { uc = (t + d < 256) ? s_sc[t + d] : 0u; fs = (t + d < 256) ? s_ss[t + d] : 0.0f; }
        __syncthreads();
        if (t < 256) { s_sc[t] += uc; s_ss[t] += fs; }
        __syncthreads();
    }
    if (t < 256) {
        unsigned int run = (t < 255) ? s_sc[t + 1] : 0u;
        float runs = (t < 255) ? s_ss[t + 1] : 0.0f;
#pragma unroll
        for (int j = 15; j >= 0; --j) {
            const unsigned int prev = run; const float prevs = runs;
            run += cb[j]; runs += sb[j];
            if (run >= target && prev < target) {
                s_res[0] = (unsigned int)(t * 16 + j); s_res[1] = prev; *s_resf = prevs;
            }
        }
    }
    __syncthreads();
    *c = s_res[0]; *cab = s_res[1]; *sab = *s_resf;
    __syncthreads();
}

// per-anchor epilogue: key write + LDS L1 hist + pos-path box loss accumulation
__device__ __forceinline__ void epi(
    int b, int i, float4 a4, int arg, bool pos, bool neg,
    const float* __restrict__ cls, const float* __restrict__ reg,
    const float4* sbox, unsigned int* __restrict__ keys,
    unsigned int* hc8, float* hs8, float& posv, float& boxv)
{
    const float2 cv = ((const float2*)cls)[(size_t)b * NA + i];
    unsigned int key = 0u;   // excluded anchors: key 0
    if (neg) {
        const float nl = -cv.y;
        key = f2key(nl);
        atomicAdd(&hc8[key >> 24], 1u);
        atomicAdd(&hs8[key >> 24], nl);
    }
    keys[(size_t)b * NA + i] = key;
    if (pos) {
        posv += -cv.x;
        const float4 g = sbox[arg];
        const float aw = a4.z - a4.x, ah = a4.w - a4.y;
        const float acx = a4.x + 0.5f * aw, acy = a4.y + 0.5f * ah;
        const float gw = g.z - g.x, gh = g.w - g.y;
        const float gcx = g.x + 0.5f * gw, gcy = g.y + 0.5f * gh;
        const float t0 = ((gcx - acx) / (aw + 1e-14f)) / 0.1f;
        const float t1 = ((gcy - acy) / (ah + 1e-14f)) / 0.1f;
        const float t2 = logf(gw / aw) / 0.2f;
        const float t3 = logf(gh / ah) / 0.2f;
        const float4 r = ((const float4*)reg)[(size_t)b * NA + i];
        const float d0 = fabsf(t0 - r.x);
        const float d1 = fabsf(t1 - r.y);
        const float d2 = fabsf(t2 - r.z);
        const float d3 = fabsf(t3 - r.w);
        const float l0 = (d0 < 1.0f) ? 0.5f * d0 * d0 : d0 - 0.5f;
        const float l1 = (d1 < 1.0f) ? 0.5f * d1 * d1 : d1 - 0.5f;
        const float l2 = (d2 < 1.0f) ? 0.5f * d2 * d2 : d2 - 0.5f;
        const float l3 = (d3 < 1.0f) ? 0.5f * d3 * d3 : d3 - 0.5f;
        boxv += l0 + l1 + l2 + l3;
    }
}

// ---------------- K1: r8 inner loop unchanged; launch_bounds min-waves 4 -> 8 ----------------
__global__ __launch_bounds__(256, 8) void k_main(
    const float* __restrict__ cls, const float* __restrict__ reg,
    const float* __restrict__ anchors, const float* __restrict__ ann,
    unsigned int* __restrict__ scal, unsigned int* __restrict__ l1cnt,
    float* __restrict__ l1sum, unsigned int* __restrict__ keys)
{
    __shared__ float4 sbox[NM];
    __shared__ unsigned int hc8[256];
    __shared__ float hs8[256];
    __shared__ unsigned int s_np, s_nn;
    __shared__ float s_ps, s_bs;

    const int b = blockIdx.y;
    const int tid = threadIdx.x;
    if (tid < NM) {
        float4 bb = ((const float4*)ann)[b * NM + tid];
        if (!(bb.x > 0.0f)) {   // invalid -> inter 0, ua inf, ratio 0 (bit-exact vs ref, r3-r9)
            bb.x = __builtin_inff(); bb.y = __builtin_inff();
            bb.z = -__builtin_inff(); bb.w = -__builtin_inff();
        }
        sbox[tid] = bb;
    }
    hc8[tid] = 0u; hs8[tid] = 0.0f;
    if (tid == 0) { s_np = 0u; s_nn = 0u; s_ps = 0.0f; s_bs = 0.0f; }
    __syncthreads();

    const int i0 = blockIdx.x * APB + tid;
    const int i1 = i0 + 256;
    float4 A0 = make_float4(0.f, 0.f, 0.f, 0.f);
    float4 A1 = make_float4(0.f, 0.f, 0.f, 0.f);
    if (i0 < NA) A0 = ((const float4*)anchors)[i0];
    if (i1 < NA) A1 = ((const float4*)anchors)[i1];

    float bi0 = -1.0f, bu0 = 1.0f, bi1 = -1.0f, bu1 = 1.0f;
    int arg0 = 0, arg1 = 0;
    bool pos0, neg0, pos1, neg1;
    {
#pragma clang fp contract(off)
        const float aa0 = (A0.z - A0.x) * (A0.w - A0.y);
        const float aa1 = (A1.z - A1.x) * (A1.w - A1.y);
#pragma unroll 1
        for (int mo = 0; mo < NM; mo += 8) {
            float4 bb[8]; float ab[8];
#pragma unroll
            for (int j = 0; j < 8; ++j) {
                bb[j] = sbox[mo + j];
                ab[j] = (bb[j].z - bb[j].x) * (bb[j].w - bb[j].y);
            }
#pragma unroll
            for (int j = 0; j < 8; ++j) {
                {
                    const float iw = fmaxf(fminf(A0.z, bb[j].z) - fmaxf(A0.x, bb[j].x), 0.0f);
                    const float ih = fmaxf(fminf(A0.w, bb[j].w) - fmaxf(A0.y, bb[j].y), 0.0f);
                    const float inter = iw * ih;
                    const float ua = fmaxf(aa0 + ab[j] - inter, 1e-8f);
                    if (inter * bu0 > bi0 * ua) { bi0 = inter; bu0 = ua; arg0 = mo + j; }
                }
                {
                    const float iw = fmaxf(fminf(A1.z, bb[j].z) - fmaxf(A1.x, bb[j].x), 0.0f);
                    const float ih = fmaxf(fminf(A1.w, bb[j].w) - fmaxf(A1.y, bb[j].y), 0.0f);
                    const float inter = iw * ih;
                    const float ua = fmaxf(aa1 + ab[j] - inter, 1e-8f);
                    if (inter * bu1 > bi1 * ua) { bi1 = inter; bu1 = ua; arg1 = mo + j; }
                }
            }
        }
        pos0 = (bi0 >= 0.5f * bu0); neg0 = (bi0 < 0.3f * bu0);
        pos1 = (bi1 >= 0.5f * bu1); neg1 = (bi1 < 0.3f * bu1);
    }

    float posv = 0.0f, boxv = 0.0f;
    if (i0 < NA) epi(b, i0, A0, arg0, pos0, neg0, cls, reg, (const float4*)sbox, keys, hc8, hs8, posv, boxv);
    else { pos0 = false; neg0 = false; }
    if (i1 < NA) epi(b, i1, A1, arg1, pos1, neg1, cls, reg, (const float4*)sbox, keys, hc8, hs8, posv, boxv);
    else { pos1 = false; neg1 = false; }

    const unsigned long long pb0 = __ballot(pos0);
    const unsigned long long pb1 = __ballot(pos1);
    const unsigned long long nb0 = __ballot(neg0);
    const unsigned long long nb1 = __ballot(neg1);
    if (pb0 | pb1) {
        for (int off = 32; off; off >>= 1) {
            posv += __shfl_xor(posv, off);
            boxv += __shfl_xor(boxv, off);
        }
    }
    if ((tid & 63) == 0) {
        const unsigned int nc = (unsigned int)(__popcll(nb0) + __popcll(nb1));
        const unsigned int pc = (unsigned int)(__popcll(pb0) + __popcll(pb1));
        if (nc) atomicAdd(&s_nn, nc);
        if (pc) { atomicAdd(&s_np, pc); atomicAdd(&s_ps, posv); atomicAdd(&s_bs, boxv); }
    }
    __syncthreads();
    unsigned int* sg = scal + b * 16;
    if (tid == 0) {
        if (s_nn) atomicAdd(&sg[1], s_nn);
        if (s_np) {
            atomicAdd(&sg[0], s_np);
            atomicAdd((float*)(sg + 2), s_ps);
            atomicAdd((float*)(sg + 3), s_bs);
        }
    }
    if (hc8[tid]) {
        atomicAdd(&l1cnt[b * 256 + tid], hc8[tid]);
        atomicAdd(&l1sum[b * 256 + tid], hs8[tid]);
    }
}

// ---------------- T1: compaction ONLY (no global histogram). 128 blocks/image. --------------
// One counter atomic per wave per 8-key batch (two-pass ballot).
__global__ __launch_bounds__(256) void k_h2c(
    const unsigned int* __restrict__ keys, unsigned int* __restrict__ scal,
    const unsigned int* __restrict__ l1c, const float* __restrict__ l1s,
    unsigned int* __restrict__ cbuf)
{
    const int b = blockIdx.x >> 7;
    const int sub = blockIdx.x & (SPB - 1);
    const int tid = threadIdx.x;
    const unsigned int k = calck(scal, b);
    if (k == 0) return;   // grid-uniform per image
    unsigned int c1, cab1; float sab1;
    wave_sel256(l1c + b * 256, l1s + b * 256, k, &c1, &cab1, &sab1);   // barrier-free

    const uint4* kp4 = (const uint4*)(keys + (size_t)b * NA);
    const int j0 = sub * 256 + tid;          // [0, 32767] < NA4
    const int j1 = j0 + SPB * 256;           // [32768, 65535]
    const uint4 v0 = kp4[j0];
    const uint4 v1 = (j1 < NA4) ? kp4[j1] : make_uint4(0, 0, 0, 0);
    const unsigned int kk[8] = {v0.x, v0.y, v0.z, v0.w, v1.x, v1.y, v1.z, v1.w};

    const int lane = tid & 63;
    bool m[8];
    unsigned long long mask[8];
    unsigned int tot = 0;
#pragma unroll
    for (int j = 0; j < 8; ++j) {
        m[j] = kk[j] && (kk[j] >> 24) == c1;
        mask[j] = __ballot(m[j]);
        tot += (unsigned int)__popcll(mask[j]);
    }
    if (tot) {
        unsigned int base = 0u;
        if (lane == 0) base = atomicAdd(scal + b * 16 + 6, tot);
        base = __shfl(base, 0);
        unsigned int* cb = cbuf + (size_t)b * NA;
        const unsigned long long lt = (lane == 63) ? ~0ull >> 1 : ((1ull << (lane + 1)) - 1ull) >> 1;
        // lt = bits strictly below `lane`
#pragma unroll
        for (int j = 0; j < 8; ++j) {
            if (m[j]) cb[base + (unsigned int)__popcll(mask[j] & lt)] = kk[j];
            base += (unsigned int)__popcll(mask[j]);
        }
    }
}

// ---------------- T2: select chain over compacted keys, 2 LDS-hist passes + finalize --------
__global__ __launch_bounds__(1024) void k_fin2(
    const unsigned int* __restrict__ scal,
    const unsigned int* __restrict__ l1c, const float* __restrict__ l1s,
    const unsigned int* __restrict__ cbuf, float* __restrict__ out)
{
    __shared__ unsigned int hc[4096];
    __shared__ float hs[4096];
    __shared__ unsigned int s_sc[256];
    __shared__ float s_ss[256];
    __shared__ unsigned int s_res[2];
    __shared__ float s_resf;

    const int b = blockIdx.x;
    const int tid = threadIdx.x;
    const unsigned int np = scal[b * 16];
    const unsigned int k = calck(scal, b);
    float s_top = 0.0f;

    if (k > 0) {   // block-uniform
        unsigned int c1, cab1; float sab1;
        wave_sel256(l1c + b * 256, l1s + b * 256, k, &c1, &cab1, &sab1);   // per-wave, redundant
        const unsigned int t2 = k - cab1;
        const unsigned int n2 = scal[b * 16 + 6];
        const unsigned int* cb = cbuf + (size_t)b * NA;

        // --- pass A: 12-bit hist of bits [23:12] over ALL compacted keys (LDS atomics only) ---
        for (int j = tid; j < 4096; j += 1024) { hc[j] = 0u; hs[j] = 0.0f; }
        __syncthreads();
        for (unsigned int base = 0; base < n2; base += 4096) {
            const unsigned int i0 = base + tid, i1 = i0 + 1024, i2 = i0 + 2048, i3 = i0 + 3072;
            const unsigned int k0 = (i0 < n2) ? cb[i0] : 0u;
            const unsigned int k1 = (i1 < n2) ? cb[i1] : 0u;
            const unsigned int k2 = (i2 < n2) ? cb[i2] : 0u;
            const unsigned int k3 = (i3 < n2) ? cb[i3] : 0u;
            if (i0 < n2) { atomicAdd(&hc[(k0 >> 12) & 0xfffu], 1u); atomicAdd(&hs[(k0 >> 12) & 0xfffu], key2f(k0)); }
            if (i1 < n2) { atomicAdd(&hc[(k1 >> 12) & 0xfffu], 1u); atomicAdd(&hs[(k1 >> 12) & 0xfffu], key2f(k1)); }
            if (i2 < n2) { atomicAdd(&hc[(k2 >> 12) & 0xfffu], 1u); atomicAdd(&hs[(k2 >> 12) & 0xfffu], key2f(k2)); }
            if (i3 < n2) { atomicAdd(&hc[(k3 >> 12) & 0xfffu], 1u); atomicAdd(&hs[(k3 >> 12) & 0xfffu], key2f(k3)); }
        }
        __syncthreads();
        unsigned int c2, cab2; float sab2;
        sel4096_lds(hc, hs, t2, s_sc, s_ss, s_res, &s_resf, &c2, &cab2, &sab2);
        const unsigned int t3 = t2 - cab2;

        // --- pass B: low-12-bit hist of keys whose bits[23:12]==c2 ---
        for (int j = tid; j < 4096; j += 1024) { hc[j] = 0u; hs[j] = 0.0f; }
        __syncthreads();
        for (unsigned int base = 0; base < n2; base += 4096) {
            const unsigned int i0 = base + tid, i1 = i0 + 1024, i2 = i0 + 2048, i3 = i0 + 3072;
            const unsigned int k0 = (i0 < n2) ? cb[i0] : 0u;
            const unsigned int k1 = (i1 < n2) ? cb[i1] : 0u;
            const unsigned int k2 = (i2 < n2) ? cb[i2] : 0u;
            const unsigned int k3 = (i3 < n2) ? cb[i3] : 0u;
            if (i0 < n2 && ((k0 >> 12) & 0xfffu) == c2) { atomicAdd(&hc[k0 & 0xfffu], 1u); atomicAdd(&hs[k0 & 0xfffu], key2f(k0)); }
            if (i1 < n2 && ((k1 >> 12) & 0xfffu) == c2) { atomicAdd(&hc[k1 & 0xfffu], 1u); atomicAdd(&hs[k1 & 0xfffu], key2f(k1)); }
            if (i2 < n2 && ((k2 >> 12) & 0xfffu) == c2) { atomicAdd(&hc[k2 & 0xfffu], 1u); atomicAdd(&hs[k2 & 0xfffu], key2f(k2)); }
            if (i3 < n2 && ((k3 >> 12) & 0xfffu) == c2) { atomicAdd(&hc[k3 & 0xfffu], 1u); atomicAdd(&hs[k3 & 0xfffu], key2f(k3)); }
        }
        __syncthreads();
        unsigned int c3, cab3; float sab3;
        sel4096_lds(hc, hs, t3, s_sc, s_ss, s_res, &s_resf, &c3, &cab3, &sab3);

        const unsigned int keyv = (c1 << 24) | (c2 << 12) | c3;
        const float v = key2f(keyv);
        const unsigned int rem = t3 - cab3;      // exact tie handling: leaf keys identical
        s_top = sab1 + sab2 + sab3 + (float)rem * v;
    }

    if (tid == 0) {
        float cls_loss = 0.0f, box_loss = 0.0f;
        if (np > 0) {
            const float* fsc = (const float*)(scal + b * 16);
            const float pos_mean = fsc[2] / (float)np;
            const float neg_mean = s_top / (float)((k > 0) ? k : 1u);
            cls_loss = pos_mean + neg_mean;
            box_loss = fsc[3] / (float)(4u * np);
        }
        out[b] = cls_loss;
        out[NB + b] = box_loss;
    }
}

extern "C" void kernel_launch(void* const* d_in, const int* in_sizes, int n_in,
                              void* d_out, int out_size, void* d_ws, size_t ws_size,
                              hipStream_t stream) {
    const float* cls     = (const float*)d_in[0];   // (B, A, 2)
    const float* reg     = (const float*)d_in[1];   // (B, A, 4)
    const float* anchors = (const float*)d_in[2];   // (1, A, 4)
    const float* ann     = (const float*)d_in[3];   // (B, M, 4)
    unsigned int* ws = (unsigned int*)d_ws;
    unsigned int* scal = ws + O_SCAL;
    unsigned int* l1c  = ws + O_L1C;   float* l1s = (float*)(ws + O_L1S);
    unsigned int* keys = ws + O_KEYS;
    unsigned int* cbuf = ws + O_CBUF;
    (void)in_sizes; (void)n_in; (void)out_size; (void)ws_size;

    hipMemsetAsync(d_ws, 0, (size_t)N_ZERO * 4, stream);
    k_main<<<dim3(CPB, NB),  256,  0, stream>>>(cls, reg, anchors, ann, scal, l1c, l1s, keys);
    k_h2c <<<dim3(NB * SPB), 256,  0, stream>>>(keys, scal, l1c, l1s, cbuf);
    k_fin2<<<dim3(NB),       1024, 0, stream>>>(scal, l1c, l1s, cbuf, (float*)d_out);
}

// Round 11
// 253.749 us; speedup vs baseline: 1.1246x; 1.0631x over previous
//
#include <hip/hip_runtime.h>
#include <stdint.h>

#define NA 200000
#define NB 8
#define NM 64
#define APB 512                 // anchors per k_main block (2 per thread) -- r6/r8 proven config
#define CPB 391                 // 391*512 = 200192 >= 200000
#define NA4 50000               // NA/4 uint4 per image
#define SPB 128                 // scan blocks per image (k_h2c)

// ---- workspace layout (dword offsets) ----
// scal: 8 images x 16 slots: [0]np [1]nn [2]ps(f32) [3]bs(f32) [6]compact_count
#define O_SCAL 0
#define O_L1C  128                   // 8 x 256
#define O_L1S  2176
#define O_KEYS 4224                  // 8 x 200000 (byte 16896, 16B-aligned)
#define O_CBUF 1604224               // 8 x 200000 compacted keys (worst case = all)
#define N_ZERO 4224                  // zero scal + L1 only (16.9 KB)

__device__ __forceinline__ unsigned int f2key(float f) {
    unsigned int u = __float_as_uint(f);
    return (u & 0x80000000u) ? ~u : (u | 0x80000000u);
}
__device__ __forceinline__ float key2f(unsigned int k) {
    return (k & 0x80000000u) ? __uint_as_float(k & 0x7fffffffu) : __uint_as_float(~k);
}
__device__ __forceinline__ unsigned int calck(const unsigned int* scal, int b) {
    const unsigned int np = scal[b * 16], nn = scal[b * 16 + 1];
    if (!np) return 0u;
    const unsigned int kp = np * 3u;
    return (kp < nn) ? kp : nn;
}

// barrier-free select over a 256-bin (cnt,sum) histogram: one wave, 4 bins/lane. (r9/r10-verified)
__device__ __forceinline__ void wave_sel256(
    const unsigned int* __restrict__ cnt, const float* __restrict__ sum,
    unsigned int target, unsigned int* c, unsigned int* cab, float* sab)
{
    const int lane = (int)(threadIdx.x & 63u);
    const uint4  c4 = ((const uint4*)cnt)[lane];
    const float4 s4 = ((const float4*)sum)[lane];
    unsigned int S = c4.x + c4.y + c4.z + c4.w;
    float Sf = s4.x + s4.y + s4.z + s4.w;
    for (int d = 1; d < 64; d <<= 1) {           // inclusive suffix scan across lanes
        const unsigned int oc = __shfl_down(S, d);
        const float of = __shfl_down(Sf, d);
        if (lane + d < 64) { S += oc; Sf += of; }
    }
    unsigned int Sn = __shfl_down(S, 1);          // suffix strictly above this lane's bins
    float Sfn = __shfl_down(Sf, 1);
    if (lane == 63) { Sn = 0u; Sfn = 0.0f; }
    const unsigned int cb[4] = {c4.x, c4.y, c4.z, c4.w};
    const float sb[4] = {s4.x, s4.y, s4.z, s4.w};
    unsigned int run = Sn; float runs = Sfn;
    bool found = false; unsigned int lc = 0, lcab = 0; float lsab = 0.0f;
#pragma unroll
    for (int j = 3; j >= 0; --j) {
        const unsigned int prev = run; const float prevs = runs;
        run += cb[j]; runs += sb[j];
        if (run >= target && prev < target) {
            found = true; lc = (unsigned int)(4 * lane + j); lcab = prev; lsab = prevs;
        }
    }
    const unsigned long long m = __ballot(found);
    const int src = __ffsll((long long)m) - 1;
    *c = __shfl(lc, src); *cab = __shfl(lcab, src); *sab = __shfl(lsab, src);
}

// exact select over 4096-bin LDS hist; 1024-thread block, threads<256 active (guarded).
__device__ void sel4096_lds(const unsigned int* hc, const float* hs, unsigned int target,
                            unsigned int* s_sc, float* s_ss, unsigned int* s_res, float* s_resf,
                            unsigned int* c, unsigned int* cab, float* sab)
{
    const int t = threadIdx.x;
    unsigned int cb[16]; float sb[16];
    if (t < 256) {
        unsigned int cc = 0; float cs = 0.0f;
#pragma unroll
        for (int j = 0; j < 16; ++j) {
            cb[j] = hc[t * 16 + j]; sb[j] = hs[t * 16 + j];
            cc += cb[j]; cs += sb[j];
        }
        s_sc[t] = cc; s_ss[t] = cs;
    }
    __syncthreads();
    for (int d = 1; d < 256; d <<= 1) {
        unsigned int uc = 0; float fs = 0.0f;
        if (t < 256) { uc = (t + d < 256) ? s_sc[t + d] : 0u; fs = (t + d < 256) ? s_ss[t + d] : 0.0f; }
        __syncthreads();
        if (t < 256) { s_sc[t] += uc; s_ss[t] += fs; }
        __syncthreads();
    }
    if (t < 256) {
        unsigned int run = (t < 255) ? s_sc[t + 1] : 0u;
        float runs = (t < 255) ? s_ss[t + 1] : 0.0f;
#pragma unroll
        for (int j = 15; j >= 0; --j) {
            const unsigned int prev = run; const float prevs = runs;
            run += cb[j]; runs += sb[j];
            if (run >= target && prev < target) {
                s_res[0] = (unsigned int)(t * 16 + j); s_res[1] = prev; *s_resf = prevs;
            }
        }
    }
    __syncthreads();
    *c = s_res[0]; *cab = s_res[1]; *sab = *s_resf;
    __syncthreads();
}

// per-anchor epilogue: key write + LDS L1 hist + pos-path box loss accumulation
__device__ __forceinline__ void epi(
    int b, int i, float4 a4, int arg, bool pos, bool neg,
    const float* __restrict__ cls, const float* __restrict__ reg,
    const float4* sbox, unsigned int* __restrict__ keys,
    unsigned int* hc8, float* hs8, float& posv, float& boxv)
{
    const float2 cv = ((const float2*)cls)[(size_t)b * NA + i];
    unsigned int key = 0u;   // excluded anchors: key 0
    if (neg) {
        const float nl = -cv.y;
        key = f2key(nl);
        atomicAdd(&hc8[key >> 24], 1u);
        atomicAdd(&hs8[key >> 24], nl);
    }
    keys[(size_t)b * NA + i] = key;
    if (pos) {
        posv += -cv.x;
        const float4 g = sbox[arg];
        const float aw = a4.z - a4.x, ah = a4.w - a4.y;
        const float acx = a4.x + 0.5f * aw, acy = a4.y + 0.5f * ah;
        const float gw = g.z - g.x, gh = g.w - g.y;
        const float gcx = g.x + 0.5f * gw, gcy = g.y + 0.5f * gh;
        const float t0 = ((gcx - acx) / (aw + 1e-14f)) / 0.1f;
        const float t1 = ((gcy - acy) / (ah + 1e-14f)) / 0.1f;
        const float t2 = logf(gw / aw) / 0.2f;
        const float t3 = logf(gh / ah) / 0.2f;
        const float4 r = ((const float4*)reg)[(size_t)b * NA + i];
        const float d0 = fabsf(t0 - r.x);
        const float d1 = fabsf(t1 - r.y);
        const float d2 = fabsf(t2 - r.z);
        const float d3 = fabsf(t3 - r.w);
        const float l0 = (d0 < 1.0f) ? 0.5f * d0 * d0 : d0 - 0.5f;
        const float l1 = (d1 < 1.0f) ? 0.5f * d1 * d1 : d1 - 0.5f;
        const float l2 = (d2 < 1.0f) ? 0.5f * d2 * d2 : d2 - 0.5f;
        const float l3 = (d3 < 1.0f) ? 0.5f * d3 * d3 : d3 - 0.5f;
        boxv += l0 + l1 + l2 + l3;
    }
}

// ---------------- K1: (256,4) proven config + VALID-BOX COMPACTION ----------------
// Invalid boxes (~25%) are removed up-front; loop runs over nvr (<=64, mult of 8)
// compacted boxes instead of 64. Equivalence: sentinel candidates (inter=0, ua=inf)
// can never win (0 > bi*inf false for bi>0, NaN-false for bi=0); nv=0 -> bi=-1 -> neg,
// matching ref's all-invalid max=-1; argmax-when-pos only selects valid boxes.
__global__ __launch_bounds__(256, 4) void k_main(
    const float* __restrict__ cls, const float* __restrict__ reg,
    const float* __restrict__ anchors, const float* __restrict__ ann,
    unsigned int* __restrict__ scal, unsigned int* __restrict__ l1cnt,
    float* __restrict__ l1sum, unsigned int* __restrict__ keys)
{
    __shared__ float4 sbox[NM];          // compacted valid boxes + sentinels
    __shared__ unsigned int s_nv;
    __shared__ unsigned int hc8[256];
    __shared__ float hs8[256];
    __shared__ unsigned int s_np, s_nn;
    __shared__ float s_ps, s_bs;

    const int b = blockIdx.y;
    const int tid = threadIdx.x;
    if (tid < NM) {   // exactly wave 0
        const float4 bb = ((const float4*)ann)[b * NM + tid];
        const bool valid = (bb.x > 0.0f);
        const unsigned long long m = __ballot(valid);
        if (valid) {
            const int p = __popcll(m & ((1ull << (tid & 63)) - 1ull));
            sbox[p] = bb;
        }
        if (tid == 0) s_nv = (unsigned int)__popcll(m);
    }
    hc8[tid] = 0u; hs8[tid] = 0.0f;
    if (tid == 0) { s_np = 0u; s_nn = 0u; s_ps = 0.0f; s_bs = 0.0f; }
    __syncthreads();
    const int nv = (int)s_nv;
    const int nvr = (nv + 7) & ~7;       // round up to multiple of 8 (<= 64)
    if (tid >= nv && tid < nvr) {        // sentinel pad: inter=0, ua=inf
        sbox[tid] = make_float4(__builtin_inff(), __builtin_inff(),
                                -__builtin_inff(), -__builtin_inff());
    }
    __syncthreads();

    const int i0 = blockIdx.x * APB + tid;
    const int i1 = i0 + 256;
    float4 A0 = make_float4(0.f, 0.f, 0.f, 0.f);
    float4 A1 = make_float4(0.f, 0.f, 0.f, 0.f);
    if (i0 < NA) A0 = ((const float4*)anchors)[i0];
    if (i1 < NA) A1 = ((const float4*)anchors)[i1];

    float bi0 = -1.0f, bu0 = 1.0f, bi1 = -1.0f, bu1 = 1.0f;
    int arg0 = 0, arg1 = 0;
    bool pos0, neg0, pos1, neg1;
    {
#pragma clang fp contract(off)
        const float aa0 = (A0.z - A0.x) * (A0.w - A0.y);
        const float aa1 = (A1.z - A1.x) * (A1.w - A1.y);
#pragma unroll 1
        for (int mo = 0; mo < nvr; mo += 8) {
            float4 bb[8]; float ab[8];
#pragma unroll
            for (int j = 0; j < 8; ++j) {
                bb[j] = sbox[mo + j];
                ab[j] = (bb[j].z - bb[j].x) * (bb[j].w - bb[j].y);
            }
#pragma unroll
            for (int j = 0; j < 8; ++j) {
                {
                    const float iw = fmaxf(fminf(A0.z, bb[j].z) - fmaxf(A0.x, bb[j].x), 0.0f);
                    const float ih = fmaxf(fminf(A0.w, bb[j].w) - fmaxf(A0.y, bb[j].y), 0.0f);
                    const float inter = iw * ih;
                    const float ua = fmaxf(aa0 + ab[j] - inter, 1e-8f);
                    if (inter * bu0 > bi0 * ua) { bi0 = inter; bu0 = ua; arg0 = mo + j; }
                }
                {
                    const float iw = fmaxf(fminf(A1.z, bb[j].z) - fmaxf(A1.x, bb[j].x), 0.0f);
                    const float ih = fmaxf(fminf(A1.w, bb[j].w) - fmaxf(A1.y, bb[j].y), 0.0f);
                    const float inter = iw * ih;
                    const float ua = fmaxf(aa1 + ab[j] - inter, 1e-8f);
                    if (inter * bu1 > bi1 * ua) { bi1 = inter; bu1 = ua; arg1 = mo + j; }
                }
            }
        }
        pos0 = (bi0 >= 0.5f * bu0); neg0 = (bi0 < 0.3f * bu0);
        pos1 = (bi1 >= 0.5f * bu1); neg1 = (bi1 < 0.3f * bu1);
    }

    float posv = 0.0f, boxv = 0.0f;
    if (i0 < NA) epi(b, i0, A0, arg0, pos0, neg0, cls, reg, (const float4*)sbox, keys, hc8, hs8, posv, boxv);
    else { pos0 = false; neg0 = false; }
    if (i1 < NA) epi(b, i1, A1, arg1, pos1, neg1, cls, reg, (const float4*)sbox, keys, hc8, hs8, posv, boxv);
    else { pos1 = false; neg1 = false; }

    const unsigned long long pb0 = __ballot(pos0);
    const unsigned long long pb1 = __ballot(pos1);
    const unsigned long long nb0 = __ballot(neg0);
    const unsigned long long nb1 = __ballot(neg1);
    if (pb0 | pb1) {
        for (int off = 32; off; off >>= 1) {
            posv += __shfl_xor(posv, off);
            boxv += __shfl_xor(boxv, off);
        }
    }
    if ((tid & 63) == 0) {
        const unsigned int nc = (unsigned int)(__popcll(nb0) + __popcll(nb1));
        const unsigned int pc = (unsigned int)(__popcll(pb0) + __popcll(pb1));
        if (nc) atomicAdd(&s_nn, nc);
        if (pc) { atomicAdd(&s_np, pc); atomicAdd(&s_ps, posv); atomicAdd(&s_bs, boxv); }
    }
    __syncthreads();
    unsigned int* sg = scal + b * 16;
    if (tid == 0) {
        if (s_nn) atomicAdd(&sg[1], s_nn);
        if (s_np) {
            atomicAdd(&sg[0], s_np);
            atomicAdd((float*)(sg + 2), s_ps);
            atomicAdd((float*)(sg + 3), s_bs);
        }
    }
    if (hc8[tid]) {
        atomicAdd(&l1cnt[b * 256 + tid], hc8[tid]);
        atomicAdd(&l1sum[b * 256 + tid], hs8[tid]);
    }
}

// ---------------- T1: compaction ONLY (r10-verified). 128 blocks/image. --------------
__global__ __launch_bounds__(256) void k_h2c(
    const unsigned int* __restrict__ keys, unsigned int* __restrict__ scal,
    const unsigned int* __restrict__ l1c, const float* __restrict__ l1s,
    unsigned int* __restrict__ cbuf)
{
    const int b = blockIdx.x >> 7;
    const int sub = blockIdx.x & (SPB - 1);
    const int tid = threadIdx.x;
    const unsigned int k = calck(scal, b);
    if (k == 0) return;   // grid-uniform per image
    unsigned int c1, cab1; float sab1;
    wave_sel256(l1c + b * 256, l1s + b * 256, k, &c1, &cab1, &sab1);   // barrier-free

    const uint4* kp4 = (const uint4*)(keys + (size_t)b * NA);
    const int j0 = sub * 256 + tid;          // [0, 32767] < NA4
    const int j1 = j0 + SPB * 256;           // [32768, 65535]
    const uint4 v0 = kp4[j0];
    const uint4 v1 = (j1 < NA4) ? kp4[j1] : make_uint4(0, 0, 0, 0);
    const unsigned int kk[8] = {v0.x, v0.y, v0.z, v0.w, v1.x, v1.y, v1.z, v1.w};

    const int lane = tid & 63;
    bool m[8];
    unsigned long long mask[8];
    unsigned int tot = 0;
#pragma unroll
    for (int j = 0; j < 8; ++j) {
        m[j] = kk[j] && (kk[j] >> 24) == c1;
        mask[j] = __ballot(m[j]);
        tot += (unsigned int)__popcll(mask[j]);
    }
    if (tot) {
        unsigned int base = 0u;
        if (lane == 0) base = atomicAdd(scal + b * 16 + 6, tot);
        base = __shfl(base, 0);
        unsigned int* cb = cbuf + (size_t)b * NA;
        const unsigned long long lt = (lane == 63) ? ~0ull >> 1 : ((1ull << (lane + 1)) - 1ull) >> 1;
#pragma unroll
        for (int j = 0; j < 8; ++j) {
            if (m[j]) cb[base + (unsigned int)__popcll(mask[j] & lt)] = kk[j];
            base += (unsigned int)__popcll(mask[j]);
        }
    }
}

// ---------------- T2: select chain over compacted keys, 2 LDS-hist passes + finalize --------
__global__ __launch_bounds__(1024) void k_fin2(
    const unsigned int* __restrict__ scal,
    const unsigned int* __restrict__ l1c, const float* __restrict__ l1s,
    const unsigned int* __restrict__ cbuf, float* __restrict__ out)
{
    __shared__ unsigned int hc[4096];
    __shared__ float hs[4096];
    __shared__ unsigned int s_sc[256];
    __shared__ float s_ss[256];
    __shared__ unsigned int s_res[2];
    __shared__ float s_resf;

    const int b = blockIdx.x;
    const int tid = threadIdx.x;
    const unsigned int np = scal[b * 16];
    const unsigned int k = calck(scal, b);
    float s_top = 0.0f;

    if (k > 0) {   // block-uniform
        unsigned int c1, cab1; float sab1;
        wave_sel256(l1c + b * 256, l1s + b * 256, k, &c1, &cab1, &sab1);   // per-wave, redundant
        const unsigned int t2 = k - cab1;
        const unsigned int n2 = scal[b * 16 + 6];
        const unsigned int* cb = cbuf + (size_t)b * NA;

        // --- pass A: 12-bit hist of bits [23:12] over ALL compacted keys (LDS atomics only) ---
        for (int j = tid; j < 4096; j += 1024) { hc[j] = 0u; hs[j] = 0.0f; }
        __syncthreads();
        for (unsigned int base = 0; base < n2; base += 4096) {
            const unsigned int i0 = base + tid, i1 = i0 + 1024, i2 = i0 + 2048, i3 = i0 + 3072;
            const unsigned int k0 = (i0 < n2) ? cb[i0] : 0u;
            const unsigned int k1 = (i1 < n2) ? cb[i1] : 0u;
            const unsigned int k2 = (i2 < n2) ? cb[i2] : 0u;
            const unsigned int k3 = (i3 < n2) ? cb[i3] : 0u;
            if (i0 < n2) { atomicAdd(&hc[(k0 >> 12) & 0xfffu], 1u); atomicAdd(&hs[(k0 >> 12) & 0xfffu], key2f(k0)); }
            if (i1 < n2) { atomicAdd(&hc[(k1 >> 12) & 0xfffu], 1u); atomicAdd(&hs[(k1 >> 12) & 0xfffu], key2f(k1)); }
            if (i2 < n2) { atomicAdd(&hc[(k2 >> 12) & 0xfffu], 1u); atomicAdd(&hs[(k2 >> 12) & 0xfffu], key2f(k2)); }
            if (i3 < n2) { atomicAdd(&hc[(k3 >> 12) & 0xfffu], 1u); atomicAdd(&hs[(k3 >> 12) & 0xfffu], key2f(k3)); }
        }
        __syncthreads();
        unsigned int c2, cab2; float sab2;
        sel4096_lds(hc, hs, t2, s_sc, s_ss, s_res, &s_resf, &c2, &cab2, &sab2);
        const unsigned int t3 = t2 - cab2;

        // --- pass B: low-12-bit hist of keys whose bits[23:12]==c2 ---
        for (int j = tid; j < 4096; j += 1024) { hc[j] = 0u; hs[j] = 0.0f; }
        __syncthreads();
        for (unsigned int base = 0; base < n2; base += 4096) {
            const unsigned int i0 = base + tid, i1 = i0 + 1024, i2 = i0 + 2048, i3 = i0 + 3072;
            const unsigned int k0 = (i0 < n2) ? cb[i0] : 0u;
            const unsigned int k1 = (i1 < n2) ? cb[i1] : 0u;
            const unsigned int k2 = (i2 < n2) ? cb[i2] : 0u;
            const unsigned int k3 = (i3 < n2) ? cb[i3] : 0u;
            if (i0 < n2 && ((k0 >> 12) & 0xfffu) == c2) { atomicAdd(&hc[k0 & 0xfffu], 1u); atomicAdd(&hs[k0 & 0xfffu], key2f(k0)); }
            if (i1 < n2 && ((k1 >> 12) & 0xfffu) == c2) { atomicAdd(&hc[k1 & 0xfffu], 1u); atomicAdd(&hs[k1 & 0xfffu], key2f(k1)); }
            if (i2 < n2 && ((k2 >> 12) & 0xfffu) == c2) { atomicAdd(&hc[k2 & 0xfffu], 1u); atomicAdd(&hs[k2 & 0xfffu], key2f(k2)); }
            if (i3 < n2 && ((k3 >> 12) & 0xfffu) == c2) { atomicAdd(&hc[k3 & 0xfffu], 1u); atomicAdd(&hs[k3 & 0xfffu], key2f(k3)); }
        }
        __syncthreads();
        unsigned int c3, cab3; float sab3;
        sel4096_lds(hc, hs, t3, s_sc, s_ss, s_res, &s_resf, &c3, &cab3, &sab3);

        const unsigned int keyv = (c1 << 24) | (c2 << 12) | c3;
        const float v = key2f(keyv);
        const unsigned int rem = t3 - cab3;      // exact tie handling: leaf keys identical
        s_top = sab1 + sab2 + sab3 + (float)rem * v;
    }

    if (tid == 0) {
        float cls_loss = 0.0f, box_loss = 0.0f;
        if (np > 0) {
            const float* fsc = (const float*)(scal + b * 16);
            const float pos_mean = fsc[2] / (float)np;
            const float neg_mean = s_top / (float)((k > 0) ? k : 1u);
            cls_loss = pos_mean + neg_mean;
            box_loss = fsc[3] / (float)(4u * np);
        }
        out[b] = cls_loss;
        out[NB + b] = box_loss;
    }
}

extern "C" void kernel_launch(void* const* d_in, const int* in_sizes, int n_in,
                              void* d_out, int out_size, void* d_ws, size_t ws_size,
                              hipStream_t stream) {
    const float* cls     = (const float*)d_in[0];   // (B, A, 2)
    const float* reg     = (const float*)d_in[1];   // (B, A, 4)
    const float* anchors = (const float*)d_in[2];   // (1, A, 4)
    const float* ann     = (const float*)d_in[3];   // (B, M, 4)
    unsigned int* ws = (unsigned int*)d_ws;
    unsigned int* scal = ws + O_SCAL;
    unsigned int* l1c  = ws + O_L1C;   float* l1s = (float*)(ws + O_L1S);
    unsigned int* keys = ws + O_KEYS;
    unsigned int* cbuf = ws + O_CBUF;
    (void)in_sizes; (void)n_in; (void)out_size; (void)ws_size;

    hipMemsetAsync(d_ws, 0, (size_t)N_ZERO * 4, stream);
    k_main<<<dim3(CPB, NB),  256,  0, stream>>>(cls, reg, anchors, ann, scal, l1c, l1s, keys);
    k_h2c <<<dim3(NB * SPB), 256,  0, stream>>>(keys, scal, l1c, l1s, cbuf);
    k_fin2<<<dim3(NB),       1024, 0, stream>>>(scal, l1c, l1s, cbuf, (float*)d_out);
}

// Round 12
// 250.907 us; speedup vs baseline: 1.1373x; 1.0113x over previous
//
#include <hip/hip_runtime.h>
#include <stdint.h>

#define NA 200000
#define NB 8
#define NM 64
#define APB 512                 // anchors per k_main block (2 per thread) -- proven config
#define CPB 391                 // 391*512 = 200192 >= 200000
#define NA4 50000               // NA/4 uint4 per image
#define SPB 128                 // scan blocks per image (k_h2c)
#define SEGCAP 25600            // per-(image,seg) cbuf capacity: exact worst-case bound
#define IMGCAP (8*SEGCAP)       // 204800 dwords per image

// ---- workspace layout (dword offsets) ----
// scal: 8 images x 16 slots: [0]np [1]nn [2]ps(f32) [3]bs(f32) [8..15] seg counters
#define O_SCAL 0
#define O_L1C  128                   // 8 x 256
#define O_L1S  2176
#define O_KEYS 4224                  // 8 x 200000 (byte 16896, 16B-aligned)
#define O_CBUF 1604224               // 8 x IMGCAP compacted keys (segmented)
#define N_ZERO 4224                  // zero scal + L1 only (16.9 KB)

__device__ __forceinline__ unsigned int f2key(float f) {
    unsigned int u = __float_as_uint(f);
    return (u & 0x80000000u) ? ~u : (u | 0x80000000u);
}
__device__ __forceinline__ float key2f(unsigned int k) {
    return (k & 0x80000000u) ? __uint_as_float(k & 0x7fffffffu) : __uint_as_float(~k);
}
__device__ __forceinline__ unsigned int calck(const unsigned int* scal, int b) {
    const unsigned int np = scal[b * 16], nn = scal[b * 16 + 1];
    if (!np) return 0u;
    const unsigned int kp = np * 3u;
    return (kp < nn) ? kp : nn;
}

// barrier-free select over a 256-bin (cnt,sum) histogram: one wave, 4 bins/lane. (r9-r11 verified)
__device__ __forceinline__ void wave_sel256(
    const unsigned int* __restrict__ cnt, const float* __restrict__ sum,
    unsigned int target, unsigned int* c, unsigned int* cab, float* sab)
{
    const int lane = (int)(threadIdx.x & 63u);
    const uint4  c4 = ((const uint4*)cnt)[lane];
    const float4 s4 = ((const float4*)sum)[lane];
    unsigned int S = c4.x + c4.y + c4.z + c4.w;
    float Sf = s4.x + s4.y + s4.z + s4.w;
    for (int d = 1; d < 64; d <<= 1) {           // inclusive suffix scan across lanes
        const unsigned int oc = __shfl_down(S, d);
        const float of = __shfl_down(Sf, d);
        if (lane + d < 64) { S += oc; Sf += of; }
    }
    unsigned int Sn = __shfl_down(S, 1);          // suffix strictly above this lane's bins
    float Sfn = __shfl_down(Sf, 1);
    if (lane == 63) { Sn = 0u; Sfn = 0.0f; }
    const unsigned int cb[4] = {c4.x, c4.y, c4.z, c4.w};
    const float sb[4] = {s4.x, s4.y, s4.z, s4.w};
    unsigned int run = Sn; float runs = Sfn;
    bool found = false; unsigned int lc = 0, lcab = 0; float lsab = 0.0f;
#pragma unroll
    for (int j = 3; j >= 0; --j) {
        const unsigned int prev = run; const float prevs = runs;
        run += cb[j]; runs += sb[j];
        if (run >= target && prev < target) {
            found = true; lc = (unsigned int)(4 * lane + j); lcab = prev; lsab = prevs;
        }
    }
    const unsigned long long m = __ballot(found);
    const int src = __ffsll((long long)m) - 1;
    *c = __shfl(lc, src); *cab = __shfl(lcab, src); *sab = __shfl(lsab, src);
}

// exact select over 4096-bin LDS hist; 1024-thread block, threads<256 active (guarded).
__device__ void sel4096_lds(const unsigned int* hc, const float* hs, unsigned int target,
                            unsigned int* s_sc, float* s_ss, unsigned int* s_res, float* s_resf,
                            unsigned int* c, unsigned int* cab, float* sab)
{
    const int t = threadIdx.x;
    unsigned int cb[16]; float sb[16];
    if (t < 256) {
        unsigned int cc = 0; float cs = 0.0f;
#pragma unroll
        for (int j = 0; j < 16; ++j) {
            cb[j] = hc[t * 16 + j]; sb[j] = hs[t * 16 + j];
            cc += cb[j]; cs += sb[j];
        }
        s_sc[t] = cc; s_ss[t] = cs;
    }
    __syncthreads();
    for (int d = 1; d < 256; d <<= 1) {
        unsigned int uc = 0; float fs = 0.0f;
        if (t < 256) { uc = (t + d < 256) ? s_sc[t + d] : 0u; fs = (t + d < 256) ? s_ss[t + d] : 0.0f; }
        __syncthreads();
        if (t < 256) { s_sc[t] += uc; s_ss[t] += fs; }
        __syncthreads();
    }
    if (t < 256) {
        unsigned int run = (t < 255) ? s_sc[t + 1] : 0u;
        float runs = (t < 255) ? s_ss[t + 1] : 0.0f;
#pragma unroll
        for (int j = 15; j >= 0; --j) {
            const unsigned int prev = run; const float prevs = runs;
            run += cb[j]; runs += sb[j];
            if (run >= target && prev < target) {
                s_res[0] = (unsigned int)(t * 16 + j); s_res[1] = prev; *s_resf = prevs;
            }
        }
    }
    __syncthreads();
    *c = s_res[0]; *cab = s_res[1]; *sab = *s_resf;
    __syncthreads();
}

// per-anchor epilogue: key write + LDS L1 hist + pos-path box loss accumulation
__device__ __forceinline__ void epi(
    int b, int i, float4 a4, int arg, bool pos, bool neg,
    const float* __restrict__ cls, const float* __restrict__ reg,
    const float4* sbox, unsigned int* __restrict__ keys,
    unsigned int* hc8, float* hs8, float& posv, float& boxv)
{
    const float2 cv = ((const float2*)cls)[(size_t)b * NA + i];
    unsigned int key = 0u;   // excluded anchors: key 0
    if (neg) {
        const float nl = -cv.y;
        key = f2key(nl);
        atomicAdd(&hc8[key >> 24], 1u);
        atomicAdd(&hs8[key >> 24], nl);
    }
    keys[(size_t)b * NA + i] = key;
    if (pos) {
        posv += -cv.x;
        const float4 g = sbox[arg];
        const float aw = a4.z - a4.x, ah = a4.w - a4.y;
        const float acx = a4.x + 0.5f * aw, acy = a4.y + 0.5f * ah;
        const float gw = g.z - g.x, gh = g.w - g.y;
        const float gcx = g.x + 0.5f * gw, gcy = g.y + 0.5f * gh;
        const float t0 = ((gcx - acx) / (aw + 1e-14f)) / 0.1f;
        const float t1 = ((gcy - acy) / (ah + 1e-14f)) / 0.1f;
        const float t2 = logf(gw / aw) / 0.2f;
        const float t3 = logf(gh / ah) / 0.2f;
        const float4 r = ((const float4*)reg)[(size_t)b * NA + i];
        const float d0 = fabsf(t0 - r.x);
        const float d1 = fabsf(t1 - r.y);
        const float d2 = fabsf(t2 - r.z);
        const float d3 = fabsf(t3 - r.w);
        const float l0 = (d0 < 1.0f) ? 0.5f * d0 * d0 : d0 - 0.5f;
        const float l1 = (d1 < 1.0f) ? 0.5f * d1 * d1 : d1 - 0.5f;
        const float l2 = (d2 < 1.0f) ? 0.5f * d2 * d2 : d2 - 0.5f;
        const float l3 = (d3 < 1.0f) ? 0.5f * d3 * d3 : d3 - 0.5f;
        boxv += l0 + l1 + l2 + l3;
    }
}

// ---------------- K1: UNCHANGED r11 (box compaction + (256,4) proven config) ----------------
__global__ __launch_bounds__(256, 4) void k_main(
    const float* __restrict__ cls, const float* __restrict__ reg,
    const float* __restrict__ anchors, const float* __restrict__ ann,
    unsigned int* __restrict__ scal, unsigned int* __restrict__ l1cnt,
    float* __restrict__ l1sum, unsigned int* __restrict__ keys)
{
    __shared__ float4 sbox[NM];          // compacted valid boxes + sentinels
    __shared__ unsigned int s_nv;
    __shared__ unsigned int hc8[256];
    __shared__ float hs8[256];
    __shared__ unsigned int s_np, s_nn;
    __shared__ float s_ps, s_bs;

    const int b = blockIdx.y;
    const int tid = threadIdx.x;
    if (tid < NM) {   // exactly wave 0
        const float4 bb = ((const float4*)ann)[b * NM + tid];
        const bool valid = (bb.x > 0.0f);
        const unsigned long long m = __ballot(valid);
        if (valid) {
            const int p = __popcll(m & ((1ull << (tid & 63)) - 1ull));
            sbox[p] = bb;
        }
        if (tid == 0) s_nv = (unsigned int)__popcll(m);
    }
    hc8[tid] = 0u; hs8[tid] = 0.0f;
    if (tid == 0) { s_np = 0u; s_nn = 0u; s_ps = 0.0f; s_bs = 0.0f; }
    __syncthreads();
    const int nv = (int)s_nv;
    const int nvr = (nv + 7) & ~7;       // round up to multiple of 8 (<= 64)
    if (tid >= nv && tid < nvr) {        // sentinel pad: inter=0, ua=inf -> can never win
        sbox[tid] = make_float4(__builtin_inff(), __builtin_inff(),
                                -__builtin_inff(), -__builtin_inff());
    }
    __syncthreads();

    const int i0 = blockIdx.x * APB + tid;
    const int i1 = i0 + 256;
    float4 A0 = make_float4(0.f, 0.f, 0.f, 0.f);
    float4 A1 = make_float4(0.f, 0.f, 0.f, 0.f);
    if (i0 < NA) A0 = ((const float4*)anchors)[i0];
    if (i1 < NA) A1 = ((const float4*)anchors)[i1];

    float bi0 = -1.0f, bu0 = 1.0f, bi1 = -1.0f, bu1 = 1.0f;
    int arg0 = 0, arg1 = 0;
    bool pos0, neg0, pos1, neg1;
    {
#pragma clang fp contract(off)
        const float aa0 = (A0.z - A0.x) * (A0.w - A0.y);
        const float aa1 = (A1.z - A1.x) * (A1.w - A1.y);
#pragma unroll 1
        for (int mo = 0; mo < nvr; mo += 8) {
            float4 bb[8]; float ab[8];
#pragma unroll
            for (int j = 0; j < 8; ++j) {
                bb[j] = sbox[mo + j];
                ab[j] = (bb[j].z - bb[j].x) * (bb[j].w - bb[j].y);
            }
#pragma unroll
            for (int j = 0; j < 8; ++j) {
                {
                    const float iw = fmaxf(fminf(A0.z, bb[j].z) - fmaxf(A0.x, bb[j].x), 0.0f);
                    const float ih = fmaxf(fminf(A0.w, bb[j].w) - fmaxf(A0.y, bb[j].y), 0.0f);
                    const float inter = iw * ih;
                    const float ua = fmaxf(aa0 + ab[j] - inter, 1e-8f);
                    if (inter * bu0 > bi0 * ua) { bi0 = inter; bu0 = ua; arg0 = mo + j; }
                }
                {
                    const float iw = fmaxf(fminf(A1.z, bb[j].z) - fmaxf(A1.x, bb[j].x), 0.0f);
                    const float ih = fmaxf(fminf(A1.w, bb[j].w) - fmaxf(A1.y, bb[j].y), 0.0f);
                    const float inter = iw * ih;
                    const float ua = fmaxf(aa1 + ab[j] - inter, 1e-8f);
                    if (inter * bu1 > bi1 * ua) { bi1 = inter; bu1 = ua; arg1 = mo + j; }
                }
            }
        }
        pos0 = (bi0 >= 0.5f * bu0); neg0 = (bi0 < 0.3f * bu0);
        pos1 = (bi1 >= 0.5f * bu1); neg1 = (bi1 < 0.3f * bu1);
    }

    float posv = 0.0f, boxv = 0.0f;
    if (i0 < NA) epi(b, i0, A0, arg0, pos0, neg0, cls, reg, (const float4*)sbox, keys, hc8, hs8, posv, boxv);
    else { pos0 = false; neg0 = false; }
    if (i1 < NA) epi(b, i1, A1, arg1, pos1, neg1, cls, reg, (const float4*)sbox, keys, hc8, hs8, posv, boxv);
    else { pos1 = false; neg1 = false; }

    const unsigned long long pb0 = __ballot(pos0);
    const unsigned long long pb1 = __ballot(pos1);
    const unsigned long long nb0 = __ballot(neg0);
    const unsigned long long nb1 = __ballot(neg1);
    if (pb0 | pb1) {
        for (int off = 32; off; off >>= 1) {
            posv += __shfl_xor(posv, off);
            boxv += __shfl_xor(boxv, off);
        }
    }
    if ((tid & 63) == 0) {
        const unsigned int nc = (unsigned int)(__popcll(nb0) + __popcll(nb1));
        const unsigned int pc = (unsigned int)(__popcll(pb0) + __popcll(pb1));
        if (nc) atomicAdd(&s_nn, nc);
        if (pc) { atomicAdd(&s_np, pc); atomicAdd(&s_ps, posv); atomicAdd(&s_bs, boxv); }
    }
    __syncthreads();
    unsigned int* sg = scal + b * 16;
    if (tid == 0) {
        if (s_nn) atomicAdd(&sg[1], s_nn);
        if (s_np) {
            atomicAdd(&sg[0], s_np);
            atomicAdd((float*)(sg + 2), s_ps);
            atomicAdd((float*)(sg + 3), s_bs);
        }
    }
    if (hc8[tid]) {
        atomicAdd(&l1cnt[b * 256 + tid], hc8[tid]);
        atomicAdd(&l1sum[b * 256 + tid], hs8[tid]);
    }
}

// ---------------- T1: segmented compaction. 128 blocks/image, ONE atomic per block -----------
// Counter address scal[b*16+8+(sub&7)]: 8 counters/image, 16 blocks each (XCD-affine with
// round-robin dispatch). Block's 4 waves aggregate via LDS first. Segment capacity 25600 is
// the exact data-independent worst case (sum of per-block key maxima per segment).
__global__ __launch_bounds__(256) void k_h2c(
    const unsigned int* __restrict__ keys, unsigned int* __restrict__ scal,
    const unsigned int* __restrict__ l1c, const float* __restrict__ l1s,
    unsigned int* __restrict__ cbuf)
{
    __shared__ unsigned int wcnt[4];
    __shared__ unsigned int sbase;
    const int b = blockIdx.x >> 7;
    const int sub = blockIdx.x & (SPB - 1);
    const int tid = threadIdx.x;
    const unsigned int k = calck(scal, b);
    if (k == 0) return;   // grid-uniform per image
    unsigned int c1, cab1; float sab1;
    wave_sel256(l1c + b * 256, l1s + b * 256, k, &c1, &cab1, &sab1);   // barrier-free

    const uint4* kp4 = (const uint4*)(keys + (size_t)b * NA);
    const int j0 = sub * 256 + tid;          // [0, 32767] < NA4
    const int j1 = j0 + SPB * 256;           // [32768, 65535]
    const uint4 v0 = kp4[j0];
    const uint4 v1 = (j1 < NA4) ? kp4[j1] : make_uint4(0, 0, 0, 0);
    const unsigned int kk[8] = {v0.x, v0.y, v0.z, v0.w, v1.x, v1.y, v1.z, v1.w};

    const int lane = tid & 63;
    const int wave = tid >> 6;
    bool m[8];
    unsigned long long mask[8];
    unsigned int tot = 0;
#pragma unroll
    for (int j = 0; j < 8; ++j) {
        m[j] = kk[j] && (kk[j] >> 24) == c1;
        mask[j] = __ballot(m[j]);
        tot += (unsigned int)__popcll(mask[j]);
    }
    if (lane == 0) wcnt[wave] = tot;
    __syncthreads();
    if (tid == 0) {   // exclusive prefix over waves + ONE atomic per block
        unsigned int p = 0;
#pragma unroll
        for (int w = 0; w < 4; ++w) { const unsigned int t = wcnt[w]; wcnt[w] = p; p += t; }
        sbase = p ? atomicAdd(&scal[b * 16 + 8 + (sub & 7)], p) : 0u;
    }
    __syncthreads();
    unsigned int base = sbase + wcnt[wave];
    if (tot) {
        unsigned int* cb = cbuf + (size_t)b * IMGCAP + (sub & 7) * SEGCAP;
        const unsigned long long lt = (lane == 63) ? ~0ull >> 1 : ((1ull << (lane + 1)) - 1ull) >> 1;
#pragma unroll
        for (int j = 0; j < 8; ++j) {
            if (m[j]) cb[base + (unsigned int)__popcll(mask[j] & lt)] = kk[j];
            base += (unsigned int)__popcll(mask[j]);
        }
    }
}

// ---------------- T2: select chain over segmented compacted keys + finalize (8 blocks) ------
__global__ __launch_bounds__(1024) void k_fin2(
    const unsigned int* __restrict__ scal,
    const unsigned int* __restrict__ l1c, const float* __restrict__ l1s,
    const unsigned int* __restrict__ cbuf, float* __restrict__ out)
{
    __shared__ unsigned int hc[4096];
    __shared__ float hs[4096];
    __shared__ unsigned int s_sc[256];
    __shared__ float s_ss[256];
    __shared__ unsigned int s_res[2];
    __shared__ float s_resf;

    const int b = blockIdx.x;
    const int tid = threadIdx.x;
    const unsigned int np = scal[b * 16];
    const unsigned int k = calck(scal, b);
    float s_top = 0.0f;

    if (k > 0) {   // block-uniform
        unsigned int c1, cab1; float sab1;
        wave_sel256(l1c + b * 256, l1s + b * 256, k, &c1, &cab1, &sab1);
        const unsigned int t2 = k - cab1;
        unsigned int ns[8];
#pragma unroll
        for (int s = 0; s < 8; ++s) ns[s] = scal[b * 16 + 8 + s];

        // --- pass A: 12-bit hist of bits [23:12] over all segments (LDS atomics only) ---
        for (int j = tid; j < 4096; j += 1024) { hc[j] = 0u; hs[j] = 0.0f; }
        __syncthreads();
#pragma unroll 1
        for (int s = 0; s < 8; ++s) {
            const unsigned int n2 = ns[s];
            const unsigned int* cb = cbuf + (size_t)b * IMGCAP + s * SEGCAP;
            for (unsigned int base = 0; base < n2; base += 4096) {
                const unsigned int i0 = base + tid, i1 = i0 + 1024, i2 = i0 + 2048, i3 = i0 + 3072;
                const unsigned int k0 = (i0 < n2) ? cb[i0] : 0u;
                const unsigned int k1 = (i1 < n2) ? cb[i1] : 0u;
                const unsigned int k2 = (i2 < n2) ? cb[i2] : 0u;
                const unsigned int k3 = (i3 < n2) ? cb[i3] : 0u;
                if (i0 < n2) { atomicAdd(&hc[(k0 >> 12) & 0xfffu], 1u); atomicAdd(&hs[(k0 >> 12) & 0xfffu], key2f(k0)); }
                if (i1 < n2) { atomicAdd(&hc[(k1 >> 12) & 0xfffu], 1u); atomicAdd(&hs[(k1 >> 12) & 0xfffu], key2f(k1)); }
                if (i2 < n2) { atomicAdd(&hc[(k2 >> 12) & 0xfffu], 1u); atomicAdd(&hs[(k2 >> 12) & 0xfffu], key2f(k2)); }
                if (i3 < n2) { atomicAdd(&hc[(k3 >> 12) & 0xfffu], 1u); atomicAdd(&hs[(k3 >> 12) & 0xfffu], key2f(k3)); }
            }
        }
        __syncthreads();
        unsigned int c2, cab2; float sab2;
        sel4096_lds(hc, hs, t2, s_sc, s_ss, s_res, &s_resf, &c2, &cab2, &sab2);
        const unsigned int t3 = t2 - cab2;

        // --- pass B: low-12-bit hist of keys whose bits[23:12]==c2 ---
        for (int j = tid; j < 4096; j += 1024) { hc[j] = 0u; hs[j] = 0.0f; }
        __syncthreads();
#pragma unroll 1
        for (int s = 0; s < 8; ++s) {
            const unsigned int n2 = ns[s];
            const unsigned int* cb = cbuf + (size_t)b * IMGCAP + s * SEGCAP;
            for (unsigned int base = 0; base < n2; base += 4096) {
                const unsigned int i0 = base + tid, i1 = i0 + 1024, i2 = i0 + 2048, i3 = i0 + 3072;
                const unsigned int k0 = (i0 < n2) ? cb[i0] : 0u;
                const unsigned int k1 = (i1 < n2) ? cb[i1] : 0u;
                const unsigned int k2 = (i2 < n2) ? cb[i2] : 0u;
                const unsigned int k3 = (i3 < n2) ? cb[i3] : 0u;
                if (i0 < n2 && ((k0 >> 12) & 0xfffu) == c2) { atomicAdd(&hc[k0 & 0xfffu], 1u); atomicAdd(&hs[k0 & 0xfffu], key2f(k0)); }
                if (i1 < n2 && ((k1 >> 12) & 0xfffu) == c2) { atomicAdd(&hc[k1 & 0xfffu], 1u); atomicAdd(&hs[k1 & 0xfffu], key2f(k1)); }
                if (i2 < n2 && ((k2 >> 12) & 0xfffu) == c2) { atomicAdd(&hc[k2 & 0xfffu], 1u); atomicAdd(&hs[k2 & 0xfffu], key2f(k2)); }
                if (i3 < n2 && ((k3 >> 12) & 0xfffu) == c2) { atomicAdd(&hc[k3 & 0xfffu], 1u); atomicAdd(&hs[k3 & 0xfffu], key2f(k3)); }
            }
        }
        __syncthreads();
        unsigned int c3, cab3; float sab3;
        sel4096_lds(hc, hs, t3, s_sc, s_ss, s_res, &s_resf, &c3, &cab3, &sab3);

        const unsigned int keyv = (c1 << 24) | (c2 << 12) | c3;
        const float v = key2f(keyv);
        const unsigned int rem = t3 - cab3;      // exact tie handling: leaf keys identical
        s_top = sab1 + sab2 + sab3 + (float)rem * v;
    }

    if (tid == 0) {
        float cls_loss = 0.0f, box_loss = 0.0f;
        if (np > 0) {
            const float* fsc = (const float*)(scal + b * 16);
            const float pos_mean = fsc[2] / (float)np;
            const float neg_mean = s_top / (float)((k > 0) ? k : 1u);
            cls_loss = pos_mean + neg_mean;
            box_loss = fsc[3] / (float)(4u * np);
        }
        out[b] = cls_loss;
        out[NB + b] = box_loss;
    }
}

extern "C" void kernel_launch(void* const* d_in, const int* in_sizes, int n_in,
                              void* d_out, int out_size, void* d_ws, size_t ws_size,
                              hipStream_t stream) {
    const float* cls     = (const float*)d_in[0];   // (B, A, 2)
    const float* reg     = (const float*)d_in[1];   // (B, A, 4)
    const float* anchors = (const float*)d_in[2];   // (1, A, 4)
    const float* ann     = (const float*)d_in[3];   // (B, M, 4)
    unsigned int* ws = (unsigned int*)d_ws;
    unsigned int* scal = ws + O_SCAL;
    unsigned int* l1c  = ws + O_L1C;   float* l1s = (float*)(ws + O_L1S);
    unsigned int* keys = ws + O_KEYS;
    unsigned int* cbuf = ws + O_CBUF;
    (void)in_sizes; (void)n_in; (void)out_size; (void)ws_size;

    hipMemsetAsync(d_ws, 0, (size_t)N_ZERO * 4, stream);
    k_main<<<dim3(CPB, NB),  256,  0, stream>>>(cls, reg, anchors, ann, scal, l1c, l1s, keys);
    k_h2c <<<dim3(NB * SPB), 256,  0, stream>>>(keys, scal, l1c, l1s, cbuf);
    k_fin2<<<dim3(NB),       1024, 0, stream>>>(scal, l1c, l1s, cbuf, (float*)d_out);
}

// Round 13
// 195.743 us; speedup vs baseline: 1.4578x; 1.2818x over previous
//
#include <hip/hip_runtime.h>
#include <stdint.h>

#define NA 200000
#define NB 8
#define NM 64
#define APB 512                 // anchors per k_main block (2 per thread) -- proven config
#define CPB 391                 // 391*512 = 200192 >= 200000
#define NA4 50000               // NA/4 uint4 per image
#define SPB 128                 // scan blocks per image (k_h2c)
#define SEGCAP 25600            // per-(image,seg) cbuf capacity: exact worst-case bound
#define IMGCAP (8*SEGCAP)       // 204800 dwords per image

// ---- workspace layout (dword offsets) ----
// scal: 8 images x 16 slots: [0]np [1]nn [2]ps(f32) [3]bs(f32) [8..15] seg counters
#define O_SCAL 0
#define O_L1C  128                   // 8 x 256
#define O_L1S  2176
#define O_KEYS 4224                  // 8 x 200000 (byte 16896, 16B-aligned)
#define O_CBUF 1604224               // 8 x IMGCAP compacted keys (segmented)
#define N_ZERO 4224                  // zero scal + L1 only (16.9 KB)

__device__ __forceinline__ unsigned int f2key(float f) {
    unsigned int u = __float_as_uint(f);
    return (u & 0x80000000u) ? ~u : (u | 0x80000000u);
}
__device__ __forceinline__ float key2f(unsigned int k) {
    return (k & 0x80000000u) ? __uint_as_float(k & 0x7fffffffu) : __uint_as_float(~k);
}
__device__ __forceinline__ unsigned int calck(const unsigned int* scal, int b) {
    const unsigned int np = scal[b * 16], nn = scal[b * 16 + 1];
    if (!np) return 0u;
    const unsigned int kp = np * 3u;
    return (kp < nn) ? kp : nn;
}

// barrier-free select over a 256-bin (cnt,sum) histogram: one wave, 4 bins/lane. (r9-r12 verified)
__device__ __forceinline__ void wave_sel256(
    const unsigned int* __restrict__ cnt, const float* __restrict__ sum,
    unsigned int target, unsigned int* c, unsigned int* cab, float* sab)
{
    const int lane = (int)(threadIdx.x & 63u);
    const uint4  c4 = ((const uint4*)cnt)[lane];
    const float4 s4 = ((const float4*)sum)[lane];
    unsigned int S = c4.x + c4.y + c4.z + c4.w;
    float Sf = s4.x + s4.y + s4.z + s4.w;
    for (int d = 1; d < 64; d <<= 1) {           // inclusive suffix scan across lanes
        const unsigned int oc = __shfl_down(S, d);
        const float of = __shfl_down(Sf, d);
        if (lane + d < 64) { S += oc; Sf += of; }
    }
    unsigned int Sn = __shfl_down(S, 1);          // suffix strictly above this lane's bins
    float Sfn = __shfl_down(Sf, 1);
    if (lane == 63) { Sn = 0u; Sfn = 0.0f; }
    const unsigned int cb[4] = {c4.x, c4.y, c4.z, c4.w};
    const float sb[4] = {s4.x, s4.y, s4.z, s4.w};
    unsigned int run = Sn; float runs = Sfn;
    bool found = false; unsigned int lc = 0, lcab = 0; float lsab = 0.0f;
#pragma unroll
    for (int j = 3; j >= 0; --j) {
        const unsigned int prev = run; const float prevs = runs;
        run += cb[j]; runs += sb[j];
        if (run >= target && prev < target) {
            found = true; lc = (unsigned int)(4 * lane + j); lcab = prev; lsab = prevs;
        }
    }
    const unsigned long long m = __ballot(found);
    const int src = __ffsll((long long)m) - 1;
    *c = __shfl(lc, src); *cab = __shfl(lcab, src); *sab = __shfl(lsab, src);
}

// single-wave two-level select over a 4096-bin COUNT histogram in LDS. Zero barriers.
// Returns crossing bin and count strictly above it. target >= 1, total >= target.
__device__ __forceinline__ void wave_sel4096_cnt(
    const unsigned int* hc, unsigned int target, unsigned int* bin, unsigned int* cab)
{
    const int lane = (int)(threadIdx.x & 63u);
    unsigned int cs = 0;
    const uint4* p = (const uint4*)(hc + lane * 64);   // lane owns bins [64*lane, 64*lane+64)
#pragma unroll
    for (int j = 0; j < 16; ++j) { const uint4 u = p[j]; cs += u.x + u.y + u.z + u.w; }
    unsigned int S = cs;
    for (int d = 1; d < 64; d <<= 1) { const unsigned int o = __shfl_down(S, d); if (lane + d < 64) S += o; }
    unsigned int Sn = __shfl_down(S, 1); if (lane == 63) Sn = 0u;
    const bool f1 = (S >= target) && (Sn < target);    // unique crossing chunk
    const unsigned long long m1 = __ballot(f1);
    const int chunk = __ffsll((long long)m1) - 1;
    const unsigned int above = __shfl(Sn, chunk);
    unsigned int S2 = hc[chunk * 64 + lane];
    for (int d = 1; d < 64; d <<= 1) { const unsigned int o = __shfl_down(S2, d); if (lane + d < 64) S2 += o; }
    unsigned int S2n = __shfl_down(S2, 1); if (lane == 63) S2n = 0u;
    const bool f2 = (above + S2 >= target) && (above + S2n < target);
    const unsigned long long m2 = __ballot(f2);
    const int l2 = __ffsll((long long)m2) - 1;
    *bin = (unsigned int)(chunk * 64 + l2);
    *cab = above + __shfl(S2n, l2);
}

// per-anchor epilogue: key write + LDS L1 hist + pos-path box loss accumulation
__device__ __forceinline__ void epi(
    int b, int i, float4 a4, int arg, bool pos, bool neg,
    const float* __restrict__ cls, const float* __restrict__ reg,
    const float4* sbox, unsigned int* __restrict__ keys,
    unsigned int* hc8, float* hs8, float& posv, float& boxv)
{
    const float2 cv = ((const float2*)cls)[(size_t)b * NA + i];
    unsigned int key = 0u;   // excluded anchors: key 0
    if (neg) {
        const float nl = -cv.y;
        key = f2key(nl);
        atomicAdd(&hc8[key >> 24], 1u);
        atomicAdd(&hs8[key >> 24], nl);
    }
    keys[(size_t)b * NA + i] = key;
    if (pos) {
        posv += -cv.x;
        const float4 g = sbox[arg];
        const float aw = a4.z - a4.x, ah = a4.w - a4.y;
        const float acx = a4.x + 0.5f * aw, acy = a4.y + 0.5f * ah;
        const float gw = g.z - g.x, gh = g.w - g.y;
        const float gcx = g.x + 0.5f * gw, gcy = g.y + 0.5f * gh;
        const float t0 = ((gcx - acx) / (aw + 1e-14f)) / 0.1f;
        const float t1 = ((gcy - acy) / (ah + 1e-14f)) / 0.1f;
        const float t2 = logf(gw / aw) / 0.2f;
        const float t3 = logf(gh / ah) / 0.2f;
        const float4 r = ((const float4*)reg)[(size_t)b * NA + i];
        const float d0 = fabsf(t0 - r.x);
        const float d1 = fabsf(t1 - r.y);
        const float d2 = fabsf(t2 - r.z);
        const float d3 = fabsf(t3 - r.w);
        const float l0 = (d0 < 1.0f) ? 0.5f * d0 * d0 : d0 - 0.5f;
        const float l1 = (d1 < 1.0f) ? 0.5f * d1 * d1 : d1 - 0.5f;
        const float l2 = (d2 < 1.0f) ? 0.5f * d2 * d2 : d2 - 0.5f;
        const float l3 = (d3 < 1.0f) ? 0.5f * d3 * d3 : d3 - 0.5f;
        boxv += l0 + l1 + l2 + l3;
    }
}

// ---------------- K1: UNCHANGED r11/r12 (box compaction + (256,4) proven config) -------------
__global__ __launch_bounds__(256, 4) void k_main(
    const float* __restrict__ cls, const float* __restrict__ reg,
    const float* __restrict__ anchors, const float* __restrict__ ann,
    unsigned int* __restrict__ scal, unsigned int* __restrict__ l1cnt,
    float* __restrict__ l1sum, unsigned int* __restrict__ keys)
{
    __shared__ float4 sbox[NM];          // compacted valid boxes + sentinels
    __shared__ unsigned int s_nv;
    __shared__ unsigned int hc8[256];
    __shared__ float hs8[256];
    __shared__ unsigned int s_np, s_nn;
    __shared__ float s_ps, s_bs;

    const int b = blockIdx.y;
    const int tid = threadIdx.x;
    if (tid < NM) {   // exactly wave 0
        const float4 bb = ((const float4*)ann)[b * NM + tid];
        const bool valid = (bb.x > 0.0f);
        const unsigned long long m = __ballot(valid);
        if (valid) {
            const int p = __popcll(m & ((1ull << (tid & 63)) - 1ull));
            sbox[p] = bb;
        }
        if (tid == 0) s_nv = (unsigned int)__popcll(m);
    }
    hc8[tid] = 0u; hs8[tid] = 0.0f;
    if (tid == 0) { s_np = 0u; s_nn = 0u; s_ps = 0.0f; s_bs = 0.0f; }
    __syncthreads();
    const int nv = (int)s_nv;
    const int nvr = (nv + 7) & ~7;       // round up to multiple of 8 (<= 64)
    if (tid >= nv && tid < nvr) {        // sentinel pad: inter=0, ua=inf -> can never win
        sbox[tid] = make_float4(__builtin_inff(), __builtin_inff(),
                                -__builtin_inff(), -__builtin_inff());
    }
    __syncthreads();

    const int i0 = blockIdx.x * APB + tid;
    const int i1 = i0 + 256;
    float4 A0 = make_float4(0.f, 0.f, 0.f, 0.f);
    float4 A1 = make_float4(0.f, 0.f, 0.f, 0.f);
    if (i0 < NA) A0 = ((const float4*)anchors)[i0];
    if (i1 < NA) A1 = ((const float4*)anchors)[i1];

    float bi0 = -1.0f, bu0 = 1.0f, bi1 = -1.0f, bu1 = 1.0f;
    int arg0 = 0, arg1 = 0;
    bool pos0, neg0, pos1, neg1;
    {
#pragma clang fp contract(off)
        const float aa0 = (A0.z - A0.x) * (A0.w - A0.y);
        const float aa1 = (A1.z - A1.x) * (A1.w - A1.y);
#pragma unroll 1
        for (int mo = 0; mo < nvr; mo += 8) {
            float4 bb[8]; float ab[8];
#pragma unroll
            for (int j = 0; j < 8; ++j) {
                bb[j] = sbox[mo + j];
                ab[j] = (bb[j].z - bb[j].x) * (bb[j].w - bb[j].y);
            }
#pragma unroll
            for (int j = 0; j < 8; ++j) {
                {
                    const float iw = fmaxf(fminf(A0.z, bb[j].z) - fmaxf(A0.x, bb[j].x), 0.0f);
                    const float ih = fmaxf(fminf(A0.w, bb[j].w) - fmaxf(A0.y, bb[j].y), 0.0f);
                    const float inter = iw * ih;
                    const float ua = fmaxf(aa0 + ab[j] - inter, 1e-8f);
                    if (inter * bu0 > bi0 * ua) { bi0 = inter; bu0 = ua; arg0 = mo + j; }
                }
                {
                    const float iw = fmaxf(fminf(A1.z, bb[j].z) - fmaxf(A1.x, bb[j].x), 0.0f);
                    const float ih = fmaxf(fminf(A1.w, bb[j].w) - fmaxf(A1.y, bb[j].y), 0.0f);
                    const float inter = iw * ih;
                    const float ua = fmaxf(aa1 + ab[j] - inter, 1e-8f);
                    if (inter * bu1 > bi1 * ua) { bi1 = inter; bu1 = ua; arg1 = mo + j; }
                }
            }
        }
        pos0 = (bi0 >= 0.5f * bu0); neg0 = (bi0 < 0.3f * bu0);
        pos1 = (bi1 >= 0.5f * bu1); neg1 = (bi1 < 0.3f * bu1);
    }

    float posv = 0.0f, boxv = 0.0f;
    if (i0 < NA) epi(b, i0, A0, arg0, pos0, neg0, cls, reg, (const float4*)sbox, keys, hc8, hs8, posv, boxv);
    else { pos0 = false; neg0 = false; }
    if (i1 < NA) epi(b, i1, A1, arg1, pos1, neg1, cls, reg, (const float4*)sbox, keys, hc8, hs8, posv, boxv);
    else { pos1 = false; neg1 = false; }

    const unsigned long long pb0 = __ballot(pos0);
    const unsigned long long pb1 = __ballot(pos1);
    const unsigned long long nb0 = __ballot(neg0);
    const unsigned long long nb1 = __ballot(neg1);
    if (pb0 | pb1) {
        for (int off = 32; off; off >>= 1) {
            posv += __shfl_xor(posv, off);
            boxv += __shfl_xor(boxv, off);
        }
    }
    if ((tid & 63) == 0) {
        const unsigned int nc = (unsigned int)(__popcll(nb0) + __popcll(nb1));
        const unsigned int pc = (unsigned int)(__popcll(pb0) + __popcll(pb1));
        if (nc) atomicAdd(&s_nn, nc);
        if (pc) { atomicAdd(&s_np, pc); atomicAdd(&s_ps, posv); atomicAdd(&s_bs, boxv); }
    }
    __syncthreads();
    unsigned int* sg = scal + b * 16;
    if (tid == 0) {
        if (s_nn) atomicAdd(&sg[1], s_nn);
        if (s_np) {
            atomicAdd(&sg[0], s_np);
            atomicAdd((float*)(sg + 2), s_ps);
            atomicAdd((float*)(sg + 3), s_bs);
        }
    }
    if (hc8[tid]) {
        atomicAdd(&l1cnt[b * 256 + tid], hc8[tid]);
        atomicAdd(&l1sum[b * 256 + tid], hs8[tid]);
    }
}

// ---------------- T1: UNCHANGED r12 segmented compaction (1 atomic/block, 8 ctrs/image) ------
__global__ __launch_bounds__(256) void k_h2c(
    const unsigned int* __restrict__ keys, unsigned int* __restrict__ scal,
    const unsigned int* __restrict__ l1c, const float* __restrict__ l1s,
    unsigned int* __restrict__ cbuf)
{
    __shared__ unsigned int wcnt[4];
    __shared__ unsigned int sbase;
    const int b = blockIdx.x >> 7;
    const int sub = blockIdx.x & (SPB - 1);
    const int tid = threadIdx.x;
    const unsigned int k = calck(scal, b);
    if (k == 0) return;   // grid-uniform per image
    unsigned int c1, cab1; float sab1;
    wave_sel256(l1c + b * 256, l1s + b * 256, k, &c1, &cab1, &sab1);   // barrier-free

    const uint4* kp4 = (const uint4*)(keys + (size_t)b * NA);
    const int j0 = sub * 256 + tid;          // [0, 32767] < NA4
    const int j1 = j0 + SPB * 256;           // [32768, 65535]
    const uint4 v0 = kp4[j0];
    const uint4 v1 = (j1 < NA4) ? kp4[j1] : make_uint4(0, 0, 0, 0);
    const unsigned int kk[8] = {v0.x, v0.y, v0.z, v0.w, v1.x, v1.y, v1.z, v1.w};

    const int lane = tid & 63;
    const int wave = tid >> 6;
    bool m[8];
    unsigned long long mask[8];
    unsigned int tot = 0;
#pragma unroll
    for (int j = 0; j < 8; ++j) {
        m[j] = kk[j] && (kk[j] >> 24) == c1;
        mask[j] = __ballot(m[j]);
        tot += (unsigned int)__popcll(mask[j]);
    }
    if (lane == 0) wcnt[wave] = tot;
    __syncthreads();
    if (tid == 0) {   // exclusive prefix over waves + ONE atomic per block
        unsigned int p = 0;
#pragma unroll
        for (int w = 0; w < 4; ++w) { const unsigned int t = wcnt[w]; wcnt[w] = p; p += t; }
        sbase = p ? atomicAdd(&scal[b * 16 + 8 + (sub & 7)], p) : 0u;
    }
    __syncthreads();
    unsigned int base = sbase + wcnt[wave];
    if (tot) {
        unsigned int* cb = cbuf + (size_t)b * IMGCAP + (sub & 7) * SEGCAP;
        const unsigned long long lt = (lane == 63) ? ~0ull >> 1 : ((1ull << (lane + 1)) - 1ull) >> 1;
#pragma unroll
        for (int j = 0; j < 8; ++j) {
            if (m[j]) cb[base + (unsigned int)__popcll(mask[j] & lt)] = kk[j];
            base += (unsigned int)__popcll(mask[j]);
        }
    }
}

// ---------------- T2 v3: count-hist radix + direct sum. ~10 barriers, zero fp LDS atomics ----
__global__ __launch_bounds__(1024) void k_fin2(
    const unsigned int* __restrict__ scal,
    const unsigned int* __restrict__ l1c, const float* __restrict__ l1s,
    const unsigned int* __restrict__ cbuf, float* __restrict__ out)
{
    __shared__ unsigned int hc[4096];
    __shared__ unsigned int s_sel[2];
    __shared__ float spart[16];

    const int b = blockIdx.x;
    const int tid = threadIdx.x;
    const unsigned int np = scal[b * 16];
    const unsigned int k = calck(scal, b);
    float s_top = 0.0f;

    if (k > 0) {   // block-uniform
        unsigned int c1, cab1; float sab1;
        wave_sel256(l1c + b * 256, l1s + b * 256, k, &c1, &cab1, &sab1);   // redundant per wave
        const unsigned int t2 = k - cab1;
        unsigned int ns[8];
#pragma unroll
        for (int s = 0; s < 8; ++s) ns[s] = scal[b * 16 + 8 + s];

        // --- pass A: count hist of bits [23:12] (all cbuf keys have top byte == c1) ---
        for (int j = tid; j < 4096; j += 1024) hc[j] = 0u;
        __syncthreads();
#pragma unroll 1
        for (int s = 0; s < 8; ++s) {
            const unsigned int n2 = ns[s];
            const unsigned int* cb = cbuf + (size_t)b * IMGCAP + s * SEGCAP;
            for (unsigned int base = 0; base < n2; base += 4096) {
                const unsigned int i0 = base + tid, i1 = i0 + 1024, i2 = i0 + 2048, i3 = i0 + 3072;
                const unsigned int k0 = (i0 < n2) ? cb[i0] : 0u;
                const unsigned int k1 = (i1 < n2) ? cb[i1] : 0u;
                const unsigned int k2 = (i2 < n2) ? cb[i2] : 0u;
                const unsigned int k3 = (i3 < n2) ? cb[i3] : 0u;
                if (i0 < n2) atomicAdd(&hc[(k0 >> 12) & 0xfffu], 1u);
                if (i1 < n2) atomicAdd(&hc[(k1 >> 12) & 0xfffu], 1u);
                if (i2 < n2) atomicAdd(&hc[(k2 >> 12) & 0xfffu], 1u);
                if (i3 < n2) atomicAdd(&hc[(k3 >> 12) & 0xfffu], 1u);
            }
        }
        __syncthreads();
        if (tid < 64) {   // wave 0 only: barrier-free select, LDS broadcast
            unsigned int c2w, cab2w;
            wave_sel4096_cnt(hc, t2, &c2w, &cab2w);
            if (tid == 0) { s_sel[0] = c2w; s_sel[1] = cab2w; }
        }
        __syncthreads();
        const unsigned int c2 = s_sel[0];
        const unsigned int t3 = t2 - s_sel[1];
        __syncthreads();   // all waves have read s_sel/hc before reuse

        // --- pass B: count hist of low 12 bits for keys with mid-12 == c2 ---
        for (int j = tid; j < 4096; j += 1024) hc[j] = 0u;
        __syncthreads();
#pragma unroll 1
        for (int s = 0; s < 8; ++s) {
            const unsigned int n2 = ns[s];
            const unsigned int* cb = cbuf + (size_t)b * IMGCAP + s * SEGCAP;
            for (unsigned int base = 0; base < n2; base += 4096) {
                const unsigned int i0 = base + tid, i1 = i0 + 1024, i2 = i0 + 2048, i3 = i0 + 3072;
                const unsigned int k0 = (i0 < n2) ? cb[i0] : 0u;
                const unsigned int k1 = (i1 < n2) ? cb[i1] : 0u;
                const unsigned int k2 = (i2 < n2) ? cb[i2] : 0u;
                const unsigned int k3 = (i3 < n2) ? cb[i3] : 0u;
                if (i0 < n2 && ((k0 >> 12) & 0xfffu) == c2) atomicAdd(&hc[k0 & 0xfffu], 1u);
                if (i1 < n2 && ((k1 >> 12) & 0xfffu) == c2) atomicAdd(&hc[k1 & 0xfffu], 1u);
                if (i2 < n2 && ((k2 >> 12) & 0xfffu) == c2) atomicAdd(&hc[k2 & 0xfffu], 1u);
                if (i3 < n2 && ((k3 >> 12) & 0xfffu) == c2) atomicAdd(&hc[k3 & 0xfffu], 1u);
            }
        }
        __syncthreads();
        if (tid < 64) {
            unsigned int c3w, cab3w;
            wave_sel4096_cnt(hc, t3, &c3w, &cab3w);
            if (tid == 0) { s_sel[0] = c3w; s_sel[1] = cab3w; }
        }
        __syncthreads();
        const unsigned int keyv = (c1 << 24) | (c2 << 12) | s_sel[0];
        const unsigned int rem = t3 - s_sel[1];   // exact ties at threshold
        const float v = key2f(keyv);

        // --- pass C: direct sum of keys strictly above keyv (no atomics) ---
        float ls = 0.0f;
#pragma unroll 1
        for (int s = 0; s < 8; ++s) {
            const unsigned int n2 = ns[s];
            const unsigned int* cb = cbuf + (size_t)b * IMGCAP + s * SEGCAP;
            for (unsigned int base = 0; base < n2; base += 4096) {
                const unsigned int i0 = base + tid, i1 = i0 + 1024, i2 = i0 + 2048, i3 = i0 + 3072;
                const unsigned int k0 = (i0 < n2) ? cb[i0] : 0u;
                const unsigned int k1 = (i1 < n2) ? cb[i1] : 0u;
                const unsigned int k2 = (i2 < n2) ? cb[i2] : 0u;
                const unsigned int k3 = (i3 < n2) ? cb[i3] : 0u;
                if (k0 > keyv) ls += key2f(k0);   // key 0 never > keyv
                if (k1 > keyv) ls += key2f(k1);
                if (k2 > keyv) ls += key2f(k2);
                if (k3 > keyv) ls += key2f(k3);
            }
        }
        for (int off = 32; off; off >>= 1) ls += __shfl_xor(ls, off);
        if ((tid & 63) == 0) spart[tid >> 6] = ls;
        __syncthreads();
        if (tid == 0) {
            float S = 0.0f;
#pragma unroll
            for (int w = 0; w < 16; ++w) S += spart[w];
            s_top = sab1 + S + (float)rem * v;
        }
    }

    if (tid == 0) {
        float cls_loss = 0.0f, box_loss = 0.0f;
        if (np > 0) {
            const float* fsc = (const float*)(scal + b * 16);
            const float pos_mean = fsc[2] / (float)np;
            const float neg_mean = s_top / (float)((k > 0) ? k : 1u);
            cls_loss = pos_mean + neg_mean;
            box_loss = fsc[3] / (float)(4u * np);
        }
        out[b] = cls_loss;
        out[NB + b] = box_loss;
    }
}

extern "C" void kernel_launch(void* const* d_in, const int* in_sizes, int n_in,
                              void* d_out, int out_size, void* d_ws, size_t ws_size,
                              hipStream_t stream) {
    const float* cls     = (const float*)d_in[0];   // (B, A, 2)
    const float* reg     = (const float*)d_in[1];   // (B, A, 4)
    const float* anchors = (const float*)d_in[2];   // (1, A, 4)
    const float* ann     = (const float*)d_in[3];   // (B, M, 4)
    unsigned int* ws = (unsigned int*)d_ws;
    unsigned int* scal = ws + O_SCAL;
    unsigned int* l1c  = ws + O_L1C;   float* l1s = (float*)(ws + O_L1S);
    unsigned int* keys = ws + O_KEYS;
    unsigned int* cbuf = ws + O_CBUF;
    (void)in_sizes; (void)n_in; (void)out_size; (void)ws_size;

    hipMemsetAsync(d_ws, 0, (size_t)N_ZERO * 4, stream);
    k_main<<<dim3(CPB, NB),  256,  0, stream>>>(cls, reg, anchors, ann, scal, l1c, l1s, keys);
    k_h2c <<<dim3(NB * SPB), 256,  0, stream>>>(keys, scal, l1c, l1s, cbuf);
    k_fin2<<<dim3(NB),       1024, 0, stream>>>(scal, l1c, l1s, cbuf, (float*)d_out);
}